// Round 2
// baseline (1052.916 us; speedup 1.0000x reference)
//
#include <hip/hip_runtime.h>
#include <stdint.h>

typedef unsigned short ushort_t;
typedef __attribute__((ext_vector_type(4))) float f32x4;
typedef __attribute__((ext_vector_type(2))) float f32x2;
typedef __attribute__((ext_vector_type(8))) __bf16 bf16x8;
typedef __attribute__((ext_vector_type(4))) unsigned short u16x4;
typedef __attribute__((ext_vector_type(8))) unsigned short u16x8;

#define DEV __device__ __forceinline__

// async global->LDS, 16B per lane. Active lanes always start at lane 0 in all
// our call sites, so HW's (uniform base + laneID*16) matches per-lane pointers.
DEV void gload_lds16(const void* g, void* l) {
  __builtin_amdgcn_global_load_lds(
      (const __attribute__((address_space(1))) uint32_t*)(uintptr_t)(g),
      (__attribute__((address_space(3))) uint32_t*)(uintptr_t)(l), 16, 0, 0);
}

DEV ushort_t f2bf(float f) {
  union { float f; uint32_t u; } x; x.f = f;
  x.u += 0x7fffu + ((x.u >> 16) & 1u);   // RNE
  return (ushort_t)(x.u >> 16);
}

DEV float bf2f(ushort_t u) {
  union { uint32_t u; float f; } x; x.u = (uint32_t)u << 16; return x.f;
}

DEV float siluf(float x) { return x / (1.f + expf(-x)); }

// ---------------- sentinel fill (diagnostic) ----------------------------------
__global__ __launch_bounds__(256) void fill_kernel(float* p, float v, int n) {
  int i = blockIdx.x * 256 + threadIdx.x;
  if (i < n) p[i] = v;
}

// ---------------- f32 -> bf16 convert (with zero tail padding) ---------------
__global__ __launch_bounds__(256) void cvt_bf16_kernel(const float* __restrict__ src,
                                                       ushort_t* __restrict__ dst,
                                                       int n_src4, int n_dst4) {
  int i = blockIdx.x * 256 + threadIdx.x;
  if (i >= n_dst4) return;
  f32x4 v;
  if (i < n_src4) v = *(const f32x4*)(src + (size_t)i * 4);
  else { v.x = 0.f; v.y = 0.f; v.z = 0.f; v.w = 0.f; }
  u16x4 o;
  o.x = f2bf(v.x); o.y = f2bf(v.y); o.z = f2bf(v.z); o.w = f2bf(v.w);
  *(u16x4*)(dst + (size_t)i * 4) = o;
}

// ---------------- GEMM1: proj = X * W1^T, bf16 out split into gate / xbcdt ---
// 128x128 tile, BK=32, 4 waves (2x2), 4x4 16x16x32 frags/wave (m97 structure)
__global__ __launch_bounds__(256) void gemm_in_kernel(const ushort_t* __restrict__ A,
                                                      const ushort_t* __restrict__ B,
                                                      ushort_t* __restrict__ Cgate,
                                                      ushort_t* __restrict__ Cx,
                                                      int K) {
  __shared__ __align__(16) ushort_t As[128 * 32];
  __shared__ __align__(16) ushort_t Bs[128 * 32];
  const int tid = threadIdx.x;
  const int lane = tid & 63, wid = tid >> 6;
  const int wr = wid >> 1, wc = wid & 1;
  const int lr = lane & 15, lk = lane >> 4;
  const int bm = blockIdx.x, bn = blockIdx.y;

  const int r0 = tid >> 2, c0 = (tid & 3) << 3;
  const ushort_t* Ag0 = A + (size_t)(bm * 128 + r0) * K + c0;
  const ushort_t* Ag1 = A + (size_t)(bm * 128 + r0 + 64) * K + c0;
  const ushort_t* Bg0 = B + (size_t)(bn * 128 + r0) * K + c0;
  const ushort_t* Bg1 = B + (size_t)(bn * 128 + r0 + 64) * K + c0;
  ushort_t* Al0 = &As[r0 * 32 + c0];
  ushort_t* Al1 = Al0 + 64 * 32;
  ushort_t* Bl0 = &Bs[r0 * 32 + c0];
  ushort_t* Bl1 = Bl0 + 64 * 32;

  f32x4 acc[4][4] = {};

  for (int k0 = 0; k0 < K; k0 += 32) {
    if (k0) __syncthreads();
    gload_lds16(Ag0 + k0, Al0);
    gload_lds16(Ag1 + k0, Al1);
    gload_lds16(Bg0 + k0, Bl0);
    gload_lds16(Bg1 + k0, Bl1);
    __syncthreads();
    bf16x8 af[4], bfr[4];
#pragma unroll
    for (int i = 0; i < 4; ++i)
      af[i] = *(const bf16x8*)&As[(wr * 64 + i * 16 + lr) * 32 + lk * 8];
#pragma unroll
    for (int i = 0; i < 4; ++i)
      bfr[i] = *(const bf16x8*)&Bs[(wc * 64 + i * 16 + lr) * 32 + lk * 8];
#pragma unroll
    for (int i = 0; i < 4; ++i)
#pragma unroll
      for (int j = 0; j < 4; ++j)
        acc[i][j] = __builtin_amdgcn_mfma_f32_16x16x32_bf16(af[i], bfr[j], acc[i][j], 0, 0, 0);
  }

  // D layout: col = lane&15, row = (lane>>4)*4 + reg
  ushort_t* Cd; int stride, colbase;
  if (bn < 32) { Cd = Cgate; stride = 4096; colbase = bn * 128; }
  else         { Cd = Cx;    stride = 6272; colbase = (bn - 32) * 128; }
  const int crow = bm * 128 + wr * 64 + lk * 4;
  const int ccol = colbase + wc * 64 + lr;
#pragma unroll
  for (int i = 0; i < 4; ++i)
#pragma unroll
    for (int j = 0; j < 4; ++j)
#pragma unroll
      for (int r = 0; r < 4; ++r)
        Cd[(size_t)(crow + i * 16 + r) * stride + ccol + j * 16] = f2bf(acc[i][j][r]);
}

// ---------------- GEMM2: out = Y * W2^T, f32 out ------------------------------
__global__ __launch_bounds__(256) void gemm_out_kernel(const ushort_t* __restrict__ A,
                                                       const ushort_t* __restrict__ B,
                                                       float* __restrict__ C,
                                                       int N, int K) {
  __shared__ __align__(16) ushort_t As[128 * 32];
  __shared__ __align__(16) ushort_t Bs[128 * 32];
  const int tid = threadIdx.x;
  const int lane = tid & 63, wid = tid >> 6;
  const int wr = wid >> 1, wc = wid & 1;
  const int lr = lane & 15, lk = lane >> 4;
  const int bm = blockIdx.x, bn = blockIdx.y;

  const int r0 = tid >> 2, c0 = (tid & 3) << 3;
  const ushort_t* Ag0 = A + (size_t)(bm * 128 + r0) * K + c0;
  const ushort_t* Ag1 = A + (size_t)(bm * 128 + r0 + 64) * K + c0;
  const ushort_t* Bg0 = B + (size_t)(bn * 128 + r0) * K + c0;
  const ushort_t* Bg1 = B + (size_t)(bn * 128 + r0 + 64) * K + c0;
  ushort_t* Al0 = &As[r0 * 32 + c0];
  ushort_t* Al1 = Al0 + 64 * 32;
  ushort_t* Bl0 = &Bs[r0 * 32 + c0];
  ushort_t* Bl1 = Bl0 + 64 * 32;

  f32x4 acc[4][4] = {};

  for (int k0 = 0; k0 < K; k0 += 32) {
    if (k0) __syncthreads();
    gload_lds16(Ag0 + k0, Al0);
    gload_lds16(Ag1 + k0, Al1);
    gload_lds16(Bg0 + k0, Bl0);
    gload_lds16(Bg1 + k0, Bl1);
    __syncthreads();
    bf16x8 af[4], bfr[4];
#pragma unroll
    for (int i = 0; i < 4; ++i)
      af[i] = *(const bf16x8*)&As[(wr * 64 + i * 16 + lr) * 32 + lk * 8];
#pragma unroll
    for (int i = 0; i < 4; ++i)
      bfr[i] = *(const bf16x8*)&Bs[(wc * 64 + i * 16 + lr) * 32 + lk * 8];
#pragma unroll
    for (int i = 0; i < 4; ++i)
#pragma unroll
      for (int j = 0; j < 4; ++j)
        acc[i][j] = __builtin_amdgcn_mfma_f32_16x16x32_bf16(af[i], bfr[j], acc[i][j], 0, 0, 0);
  }

  const int crow = bm * 128 + wr * 64 + lk * 4;
  const int ccol = bn * 128 + wc * 64 + lr;
#pragma unroll
  for (int i = 0; i < 4; ++i)
#pragma unroll
    for (int j = 0; j < 4; ++j)
#pragma unroll
      for (int r = 0; r < 4; ++r)
        C[(size_t)(crow + i * 16 + r) * N + ccol + j * 16] = acc[i][j][r];
}

// ---------------- causal depthwise conv (K=4) + bias + SiLU, bf16 in/out ------
// reads xbcdt cols [0,6144) (stride 6272), writes conv [4096][6144] bf16
__global__ __launch_bounds__(256) void conv_silu_kernel(const ushort_t* __restrict__ xbc,
                                                        const float* __restrict__ cw,
                                                        const float* __restrict__ cb,
                                                        ushort_t* __restrict__ out) {
  int idx = blockIdx.x * 256 + threadIdx.x;      // 4096*1536
  int c4 = (idx % 1536) << 2;
  int bt = idx / 1536;
  int t = bt & 2047;
  const ushort_t* base = xbc + (size_t)bt * 6272 + c4;
  f32x4 w0 = *(const f32x4*)&cw[(c4 + 0) * 4];
  f32x4 w1 = *(const f32x4*)&cw[(c4 + 1) * 4];
  f32x4 w2 = *(const f32x4*)&cw[(c4 + 2) * 4];
  f32x4 w3 = *(const f32x4*)&cw[(c4 + 3) * 4];
  f32x4 acc = *(const f32x4*)&cb[c4];
#pragma unroll
  for (int i = 0; i < 4; ++i) {
    int dt_ = i - 3;
    if (t + dt_ >= 0) {
      u16x4 xv = *(const u16x4*)(base + (ptrdiff_t)dt_ * 6272);
      acc.x += bf2f(xv.x) * w0[i];
      acc.y += bf2f(xv.y) * w1[i];
      acc.z += bf2f(xv.z) * w2[i];
      acc.w += bf2f(xv.w) * w3[i];
    }
  }
  u16x4 o;
  o.x = f2bf(siluf(acc.x)); o.y = f2bf(siluf(acc.y));
  o.z = f2bf(siluf(acc.z)); o.w = f2bf(siluf(acc.w));
  *(u16x4*)(out + (size_t)bt * 6144 + c4) = o;
}

// ---------------- dt: softplus + exp(A*dt), layout [H][2][BT] f32 -------------
__global__ __launch_bounds__(256) void dt_kernel(const ushort_t* __restrict__ xbc,
                                                 const float* __restrict__ dt_bias,
                                                 const float* __restrict__ Avec,
                                                 float* __restrict__ dtA) {
  int idx = blockIdx.x * 256 + threadIdx.x;      // 64*4096
  int h = idx >> 12, bt = idx & 4095;
  float v = bf2f(xbc[(size_t)bt * 6272 + 6144 + h]) + dt_bias[h];
  float sp = fmaxf(v, 0.f) + log1pf(expf(-fabsf(v)));
  float ab = expf(Avec[h] * sp);
  dtA[(h << 13) + bt] = sp;
  dtA[(h << 13) + 4096 + bt] = ab;
}

// ---------------- selective scan ----------------------------------------------
// grid 256 = B(2) x H(64) x Phalf(2). Block owns 32 p x 128 n states; thread =
// 2p x 8n = 16 states in regs. 8-step LDS blocks, triple-buffered async staging,
// prefetch issued BEFORE compute so HBM latency hides under FMA.
__global__ __launch_bounds__(256) void scan_kernel(const ushort_t* __restrict__ conv,
                                                   const float* __restrict__ dtA,
                                                   const float* __restrict__ Dvec,
                                                   ushort_t* __restrict__ yssm) {
  const int bid = blockIdx.x;
  const int ph = bid & 1;
  const int h = (bid >> 1) & 63;
  const int b = bid >> 7;
  const int g = h >> 3;
  const int tid = threadIdx.x;
  const int lane = tid & 63;
  const int wave = tid >> 6;
  const int pg = tid & 15, ng = tid >> 4;
  const int p0 = pg << 1, n0 = ng << 3;

  // per buf: x bf16[8][32] @0 (512B), B bf16[8][128] @512, C @2560, dt f32[8] @4608, ab f32[8] @4640
  __shared__ __align__(16) unsigned char sraw[3][4672];
  __shared__ __align__(16) float ypart[2][4][8][32];

  const int btbase = b << 11;
  const float* dt0 = dtA + (h << 13) + btbase;
  const float* dt1 = dt0 + 4096;
  const float Dh = Dvec[h];
  const int xcol = (h << 6) + (ph << 5);

  auto stage = [&](int tb) {
    unsigned char* dst = sraw[tb % 3];
    const int t0 = tb << 3;
    const size_t row0 = (size_t)(btbase + t0) * 6144;
#pragma unroll
    for (int j = 0; j < 2; ++j) {
      int c = tid + (j << 8);
      if (c < 292) {
        const void* src;
        if (c < 32)       { src = conv + row0 + (size_t)(c >> 2) * 6144 + xcol + ((c & 3) << 3); }
        else if (c < 160) { int r = c - 32;  src = conv + row0 + (size_t)(r >> 4) * 6144 + 4096 + (g << 7) + ((r & 15) << 3); }
        else if (c < 288) { int r = c - 160; src = conv + row0 + (size_t)(r >> 4) * 6144 + 5120 + (g << 7) + ((r & 15) << 3); }
        else if (c < 290) { src = dt0 + t0 + ((c - 288) << 2); }
        else              { src = dt1 + t0 + ((c - 290) << 2); }
        gload_lds16(src, dst + ((size_t)c << 4));
      }
    }
  };

  stage(0);
  stage(1);

  float hs0[8], hs1[8];
#pragma unroll
  for (int n = 0; n < 8; ++n) { hs0[n] = 0.f; hs1[n] = 0.f; }

  for (int tb = 0; tb < 256; ++tb) {
    __syncthreads();
    if (tb > 0) {                     // write previous block's y
      const int cur = (tb - 1) & 1;
      const int tprev = btbase + ((tb - 1) << 3);
      const int tt = tid >> 5, p = tid & 31;
      float v = ypart[cur][0][tt][p] + ypart[cur][1][tt][p] +
                ypart[cur][2][tt][p] + ypart[cur][3][tt][p];
      yssm[(size_t)(tprev + tt) * 4096 + xcol + p] = f2bf(v);
    }
    if (tb + 2 < 256) stage(tb + 2);  // issue prefetch BEFORE compute
    const ushort_t* sbu = (const ushort_t*)sraw[tb % 3];
    const float* sfs = (const float*)(sraw[tb % 3] + 4608);
    const int cur = tb & 1;
#pragma unroll
    for (int tt = 0; tt < 8; ++tt) {
      uint32_t xv = *(const uint32_t*)&sbu[(tt << 5) + p0];
      float x0 = bf2f((ushort_t)xv), x1 = bf2f((ushort_t)(xv >> 16));
      u16x8 bv = *(const u16x8*)&sbu[256 + (tt << 7) + n0];
      u16x8 cv = *(const u16x8*)&sbu[1280 + (tt << 7) + n0];
      float dtv = sfs[tt], ab = sfs[8 + tt];
      float dtx0 = dtv * x0, dtx1 = dtv * x1;
      float ys0 = 0.f, ys1 = 0.f;
#pragma unroll
      for (int n = 0; n < 8; ++n) {
        float Bn = bf2f(bv[n]), Cn = bf2f(cv[n]);
        hs0[n] = ab * hs0[n] + dtx0 * Bn; ys0 += hs0[n] * Cn;
        hs1[n] = ab * hs1[n] + dtx1 * Bn; ys1 += hs1[n] * Cn;
      }
      ys0 += __shfl_xor(ys0, 16, 64); ys0 += __shfl_xor(ys0, 32, 64);
      ys1 += __shfl_xor(ys1, 16, 64); ys1 += __shfl_xor(ys1, 32, 64);
      if (wave == 0) { ys0 += Dh * x0; ys1 += Dh * x1; }
      if ((lane >> 4) == 0) {
        f32x2 o; o.x = ys0; o.y = ys1;
        *(f32x2*)&ypart[cur][wave][tt][p0] = o;
      }
    }
  }
  __syncthreads();
  {
    const int cur = 255 & 1;
    const int tprev = btbase + (255 << 3);
    const int tt = tid >> 5, p = tid & 31;
    float v = ypart[cur][0][tt][p] + ypart[cur][1][tt][p] +
              ypart[cur][2][tt][p] + ypart[cur][3][tt][p];
    yssm[(size_t)(tprev + tt) * 4096 + xcol + p] = f2bf(v);
  }
}

// ---------------- gate * silu + RMSNorm -> bf16 -------------------------------
__global__ __launch_bounds__(256) void norm_kernel(const ushort_t* __restrict__ yssm,
                                                   const ushort_t* __restrict__ gate,
                                                   const float* __restrict__ nw,
                                                   ushort_t* __restrict__ out) {
  const int bt = blockIdx.x;
  const int tid = threadIdx.x;
  const ushort_t* y = yssm + (size_t)bt * 4096;
  const ushort_t* gt = gate + (size_t)bt * 4096;
  float vals[16];
  float ss = 0.f;
#pragma unroll
  for (int j = 0; j < 4; ++j) {
    int o = (tid + j * 256) << 2;
    u16x4 yv = *(const u16x4*)(y + o);
    u16x4 gv = *(const u16x4*)(gt + o);
#pragma unroll
    for (int e = 0; e < 4; ++e) {
      float v = bf2f(yv[e]) * siluf(bf2f(gv[e]));
      vals[j * 4 + e] = v;
      ss += v * v;
    }
  }
#pragma unroll
  for (int m = 1; m <= 32; m <<= 1) ss += __shfl_xor(ss, m, 64);
  __shared__ float red[4];
  if ((tid & 63) == 0) red[tid >> 6] = ss;
  __syncthreads();
  ss = red[0] + red[1] + red[2] + red[3];
  const float sc = rsqrtf(ss * (1.f / 4096.f) + 1e-5f);
#pragma unroll
  for (int j = 0; j < 4; ++j) {
    int o = (tid + j * 256) << 2;
    f32x4 wv = *(const f32x4*)(nw + o);
    u16x4 ov;
    ov.x = f2bf(vals[j * 4 + 0] * sc * wv.x);
    ov.y = f2bf(vals[j * 4 + 1] * sc * wv.y);
    ov.z = f2bf(vals[j * 4 + 2] * sc * wv.z);
    ov.w = f2bf(vals[j * 4 + 3] * sc * wv.w);
    *(u16x4*)(out + (size_t)bt * 4096 + o) = ov;
  }
}

// ------------------------------------------------------------------------------
extern "C" void kernel_launch(void* const* d_in, const int* in_sizes, int n_in,
                              void* d_out, int out_size, void* d_ws, size_t ws_size,
                              hipStream_t stream) {
  const float* hidden  = (const float*)d_in[0];
  const float* w_in    = (const float*)d_in[1];
  const float* conv_w  = (const float*)d_in[2];
  const float* conv_b  = (const float*)d_in[3];
  const float* Avec    = (const float*)d_in[4];
  const float* Dvec    = (const float*)d_in[5];
  const float* dt_bias = (const float*)d_in[6];
  const float* nw      = (const float*)d_in[7];
  const float* w_out   = (const float*)d_in[8];
  float* out = (float*)d_out;

  char* ws = (char*)d_ws;
  // Region map (total 162,693,120 B):
  //  A @0         22,020,096  : Xbf          -> W2bf (after gemm1)
  //  B @22020096  55,738,368  : W1bf         -> conv bf16 (50,331,648) + dtA f32 @+50,331,648 (2,097,152)
  //                                          -> ynorm bf16 @+0 (after scan)
  //  C @77758464  33,554,432  : gate bf16 [4096][4096]
  //  E @111312896 51,380,224  : xbcdt bf16 [4096][6272] -> yssm bf16 (after conv+dt)
  ushort_t* Xbf   = (ushort_t*)(ws);
  ushort_t* W1bf  = (ushort_t*)(ws + 22020096);
  ushort_t* gate  = (ushort_t*)(ws + 77758464);
  ushort_t* xbc   = (ushort_t*)(ws + 111312896);
  ushort_t* W2bf  = Xbf;
  ushort_t* convb = W1bf;
  float*    dtA   = (float*)(ws + 22020096 + 50331648);
  ushort_t* yssm  = xbc;
  ushort_t* ynorm = convb;
  const size_t NEED = 162693120;
  if (NEED > ws_size) {
    fill_kernel<<<4, 256, 0, stream>>>(out, 12345.0f, 1024);   // sentinel: ws too small
    return;
  }

  cvt_bf16_kernel<<<10752, 256, 0, stream>>>(hidden, Xbf, 2752512, 2752512);
  cvt_bf16_kernel<<<27216, 256, 0, stream>>>(w_in, W1bf, 6924288, 6967296);
  gemm_in_kernel<<<dim3(32, 81), 256, 0, stream>>>(Xbf, W1bf, gate, xbc, 2688);
  cvt_bf16_kernel<<<10752, 256, 0, stream>>>(w_out, W2bf, 2752512, 2752512);
  conv_silu_kernel<<<24576, 256, 0, stream>>>(xbc, conv_w, conv_b, convb);
  dt_kernel<<<1024, 256, 0, stream>>>(xbc, dt_bias, Avec, dtA);
  scan_kernel<<<256, 256, 0, stream>>>(convb, dtA, Dvec, yssm);
  norm_kernel<<<4096, 256, 0, stream>>>(yssm, gate, nw, ynorm);
  gemm_out_kernel<<<dim3(32, 21), 256, 0, stream>>>(ynorm, W2bf, out, 2688, 4096);
}

// Round 4
// 861.662 us; speedup vs baseline: 1.2220x; 1.2220x over previous
//
#include <hip/hip_runtime.h>
#include <stdint.h>

typedef unsigned short ushort_t;
typedef __attribute__((ext_vector_type(4))) float f32x4;
typedef __attribute__((ext_vector_type(2))) float f32x2;
typedef __attribute__((ext_vector_type(8))) __bf16 bf16x8;
typedef __attribute__((ext_vector_type(4))) unsigned short u16x4;
typedef __attribute__((ext_vector_type(8))) unsigned short u16x8;

#define DEV __device__ __forceinline__

// async global->LDS, 16B per lane. HW: dest = wave-uniform base + laneID*16.
// REQUIREMENT (m104/m108): every call site must have its wave's active lanes
// forming a prefix from lane 0 with per-lane lds ptr = base + lane*16.
DEV void gload_lds16(const void* g, void* l) {
  __builtin_amdgcn_global_load_lds(
      (const __attribute__((address_space(1))) uint32_t*)(uintptr_t)(g),
      (__attribute__((address_space(3))) uint32_t*)(uintptr_t)(l), 16, 0, 0);
}

DEV ushort_t f2bf(float f) {
  union { float f; uint32_t u; } x; x.f = f;
  x.u += 0x7fffu + ((x.u >> 16) & 1u);   // RNE
  return (ushort_t)(x.u >> 16);
}

DEV float bf2f(ushort_t u) {
  union { uint32_t u; float f; } x; x.u = (uint32_t)u << 16; return x.f;
}

DEV float siluf(float x) { return x / (1.f + expf(-x)); }

// ---------------- sentinel fill (diagnostic) ----------------------------------
__global__ __launch_bounds__(256) void fill_kernel(float* p, float v, int n) {
  int i = blockIdx.x * 256 + threadIdx.x;
  if (i < n) p[i] = v;
}

// ---------------- f32 -> bf16 convert (with zero tail padding) ---------------
__global__ __launch_bounds__(256) void cvt_bf16_kernel(const float* __restrict__ src,
                                                       ushort_t* __restrict__ dst,
                                                       int n_src4, int n_dst4) {
  int i = blockIdx.x * 256 + threadIdx.x;
  if (i >= n_dst4) return;
  f32x4 v;
  if (i < n_src4) v = *(const f32x4*)(src + (size_t)i * 4);
  else { v.x = 0.f; v.y = 0.f; v.z = 0.f; v.w = 0.f; }
  u16x4 o;
  o.x = f2bf(v.x); o.y = f2bf(v.y); o.z = f2bf(v.z); o.w = f2bf(v.w);
  *(u16x4*)(dst + (size_t)i * 4) = o;
}

// ---------------- GEMM1: proj = X * W1^T, bf16 out split into gate / xbcdt ---
__global__ __launch_bounds__(256) void gemm_in_kernel(const ushort_t* __restrict__ A,
                                                      const ushort_t* __restrict__ B,
                                                      ushort_t* __restrict__ Cgate,
                                                      ushort_t* __restrict__ Cx,
                                                      int K) {
  __shared__ __align__(16) ushort_t As[128 * 32];
  __shared__ __align__(16) ushort_t Bs[128 * 32];
  const int tid = threadIdx.x;
  const int lane = tid & 63, wid = tid >> 6;
  const int wr = wid >> 1, wc = wid & 1;
  const int lr = lane & 15, lk = lane >> 4;
  const int bm = blockIdx.x, bn = blockIdx.y;

  const int r0 = tid >> 2, c0 = (tid & 3) << 3;
  const ushort_t* Ag0 = A + (size_t)(bm * 128 + r0) * K + c0;
  const ushort_t* Ag1 = A + (size_t)(bm * 128 + r0 + 64) * K + c0;
  const ushort_t* Bg0 = B + (size_t)(bn * 128 + r0) * K + c0;
  const ushort_t* Bg1 = B + (size_t)(bn * 128 + r0 + 64) * K + c0;
  ushort_t* Al0 = &As[r0 * 32 + c0];
  ushort_t* Al1 = Al0 + 64 * 32;
  ushort_t* Bl0 = &Bs[r0 * 32 + c0];
  ushort_t* Bl1 = Bl0 + 64 * 32;

  f32x4 acc[4][4] = {};

  for (int k0 = 0; k0 < K; k0 += 32) {
    if (k0) __syncthreads();
    gload_lds16(Ag0 + k0, Al0);
    gload_lds16(Ag1 + k0, Al1);
    gload_lds16(Bg0 + k0, Bl0);
    gload_lds16(Bg1 + k0, Bl1);
    __syncthreads();
    bf16x8 af[4], bfr[4];
#pragma unroll
    for (int i = 0; i < 4; ++i)
      af[i] = *(const bf16x8*)&As[(wr * 64 + i * 16 + lr) * 32 + lk * 8];
#pragma unroll
    for (int i = 0; i < 4; ++i)
      bfr[i] = *(const bf16x8*)&Bs[(wc * 64 + i * 16 + lr) * 32 + lk * 8];
#pragma unroll
    for (int i = 0; i < 4; ++i)
#pragma unroll
      for (int j = 0; j < 4; ++j)
        acc[i][j] = __builtin_amdgcn_mfma_f32_16x16x32_bf16(af[i], bfr[j], acc[i][j], 0, 0, 0);
  }

  ushort_t* Cd; int stride, colbase;
  if (bn < 32) { Cd = Cgate; stride = 4096; colbase = bn * 128; }
  else         { Cd = Cx;    stride = 6272; colbase = (bn - 32) * 128; }
  const int crow = bm * 128 + wr * 64 + lk * 4;
  const int ccol = colbase + wc * 64 + lr;
#pragma unroll
  for (int i = 0; i < 4; ++i)
#pragma unroll
    for (int j = 0; j < 4; ++j)
#pragma unroll
      for (int r = 0; r < 4; ++r)
        Cd[(size_t)(crow + i * 16 + r) * stride + ccol + j * 16] = f2bf(acc[i][j][r]);
}

// ---------------- GEMM2: out = Y * W2^T, f32 out ------------------------------
__global__ __launch_bounds__(256) void gemm_out_kernel(const ushort_t* __restrict__ A,
                                                       const ushort_t* __restrict__ B,
                                                       float* __restrict__ C,
                                                       int N, int K) {
  __shared__ __align__(16) ushort_t As[128 * 32];
  __shared__ __align__(16) ushort_t Bs[128 * 32];
  const int tid = threadIdx.x;
  const int lane = tid & 63, wid = tid >> 6;
  const int wr = wid >> 1, wc = wid & 1;
  const int lr = lane & 15, lk = lane >> 4;
  const int bm = blockIdx.x, bn = blockIdx.y;

  const int r0 = tid >> 2, c0 = (tid & 3) << 3;
  const ushort_t* Ag0 = A + (size_t)(bm * 128 + r0) * K + c0;
  const ushort_t* Ag1 = A + (size_t)(bm * 128 + r0 + 64) * K + c0;
  const ushort_t* Bg0 = B + (size_t)(bn * 128 + r0) * K + c0;
  const ushort_t* Bg1 = B + (size_t)(bn * 128 + r0 + 64) * K + c0;
  ushort_t* Al0 = &As[r0 * 32 + c0];
  ushort_t* Al1 = Al0 + 64 * 32;
  ushort_t* Bl0 = &Bs[r0 * 32 + c0];
  ushort_t* Bl1 = Bl0 + 64 * 32;

  f32x4 acc[4][4] = {};

  for (int k0 = 0; k0 < K; k0 += 32) {
    if (k0) __syncthreads();
    gload_lds16(Ag0 + k0, Al0);
    gload_lds16(Ag1 + k0, Al1);
    gload_lds16(Bg0 + k0, Bl0);
    gload_lds16(Bg1 + k0, Bl1);
    __syncthreads();
    bf16x8 af[4], bfr[4];
#pragma unroll
    for (int i = 0; i < 4; ++i)
      af[i] = *(const bf16x8*)&As[(wr * 64 + i * 16 + lr) * 32 + lk * 8];
#pragma unroll
    for (int i = 0; i < 4; ++i)
      bfr[i] = *(const bf16x8*)&Bs[(wc * 64 + i * 16 + lr) * 32 + lk * 8];
#pragma unroll
    for (int i = 0; i < 4; ++i)
#pragma unroll
      for (int j = 0; j < 4; ++j)
        acc[i][j] = __builtin_amdgcn_mfma_f32_16x16x32_bf16(af[i], bfr[j], acc[i][j], 0, 0, 0);
  }

  const int crow = bm * 128 + wr * 64 + lk * 4;
  const int ccol = bn * 128 + wc * 64 + lr;
#pragma unroll
  for (int i = 0; i < 4; ++i)
#pragma unroll
    for (int j = 0; j < 4; ++j)
#pragma unroll
      for (int r = 0; r < 4; ++r)
        C[(size_t)(crow + i * 16 + r) * N + ccol + j * 16] = acc[i][j][r];
}

// ---------------- causal depthwise conv (K=4) + bias + SiLU, bf16 in/out ------
__global__ __launch_bounds__(256) void conv_silu_kernel(const ushort_t* __restrict__ xbc,
                                                        const float* __restrict__ cw,
                                                        const float* __restrict__ cb,
                                                        ushort_t* __restrict__ out) {
  int idx = blockIdx.x * 256 + threadIdx.x;      // 4096*1536
  int c4 = (idx % 1536) << 2;
  int bt = idx / 1536;
  int t = bt & 2047;
  const ushort_t* base = xbc + (size_t)bt * 6272 + c4;
  f32x4 w0 = *(const f32x4*)&cw[(c4 + 0) * 4];
  f32x4 w1 = *(const f32x4*)&cw[(c4 + 1) * 4];
  f32x4 w2 = *(const f32x4*)&cw[(c4 + 2) * 4];
  f32x4 w3 = *(const f32x4*)&cw[(c4 + 3) * 4];
  f32x4 acc = *(const f32x4*)&cb[c4];
#pragma unroll
  for (int i = 0; i < 4; ++i) {
    int dt_ = i - 3;
    if (t + dt_ >= 0) {
      u16x4 xv = *(const u16x4*)(base + (ptrdiff_t)dt_ * 6272);
      acc.x += bf2f(xv.x) * w0[i];
      acc.y += bf2f(xv.y) * w1[i];
      acc.z += bf2f(xv.z) * w2[i];
      acc.w += bf2f(xv.w) * w3[i];
    }
  }
  u16x4 o;
  o.x = f2bf(siluf(acc.x)); o.y = f2bf(siluf(acc.y));
  o.z = f2bf(siluf(acc.z)); o.w = f2bf(siluf(acc.w));
  *(u16x4*)(out + (size_t)bt * 6144 + c4) = o;
}

// ---------------- dt: softplus + exp(A*dt), layout [H][2][BT] f32 -------------
__global__ __launch_bounds__(256) void dt_kernel(const ushort_t* __restrict__ xbc,
                                                 const float* __restrict__ dt_bias,
                                                 const float* __restrict__ Avec,
                                                 float* __restrict__ dtA) {
  int idx = blockIdx.x * 256 + threadIdx.x;      // 64*4096
  int h = idx >> 12, bt = idx & 4095;
  float v = bf2f(xbc[(size_t)bt * 6272 + 6144 + h]) + dt_bias[h];
  float sp = fmaxf(v, 0.f) + log1pf(expf(-fabsf(v)));
  float ab = expf(Avec[h] * sp);
  dtA[(h << 13) + bt] = sp;
  dtA[(h << 13) + 4096 + bt] = ab;
}

// ---------------- chunked selective scan ---------------------------------------
// grid 2048 = B(2) x H(64) x Phalf(2) x Chunk(8), chunk = 256 steps.
// Block owns 32 p x 128 n states; thread = 2p x 8n = 16 states in regs.
// EMIT=0: scan from zero init, write final chunk state (bf16) + abprod.
// EMIT=1: scan from combined init, emit y.
// NOTE: stage() is IDENTICAL for both EMIT values — pass 1 stages C too even
// though unused. The EMIT=0 skip tried in R3 made wave-0's j=1 active lanes a
// non-prefix (32..35), violating global_load_lds's uniform-base+laneID*16
// addressing and leaving the dt/ab LDS slot unwritten -> NaN.
template <int EMIT>
__global__ __launch_bounds__(256) void scan_chunk_kernel(const ushort_t* __restrict__ conv,
                                                         const float* __restrict__ dtA,
                                                         const float* __restrict__ Dvec,
                                                         const float* __restrict__ Avec,
                                                         ushort_t* __restrict__ yssm,
                                                         ushort_t* __restrict__ hst,
                                                         float* __restrict__ abprod) {
  const int bid = blockIdx.x;
  const int ck = bid & 7;
  const int ph = (bid >> 3) & 1;
  const int h = (bid >> 4) & 63;
  const int b = bid >> 10;
  const int g = h >> 3;
  const int tid = threadIdx.x;
  const int lane = tid & 63;
  const int wave = tid >> 6;
  const int pg = tid & 15, ng = tid >> 4;
  const int p0 = pg << 1, n0 = ng << 3;

  // per buf: x bf16[8][32] @0, B bf16[8][128] @512, C @2560, dt f32[8] @4608, ab f32[8] @4640
  __shared__ __align__(16) unsigned char sraw[2][4672];
  __shared__ __align__(16) float ypart[2][4][8][32];

  const int btbase = (b << 11) + (ck << 8);
  const float* dt0 = dtA + (h << 13) + btbase;
  const float* dt1 = dt0 + 4096;
  const float Dh = Dvec[h];
  const int xcol = (h << 6) + (ph << 5);
  const size_t hbase = (size_t)bid * 4096;  // [(b,h,ph)][ck][32*128]

  auto stage = [&](int tb) {
    unsigned char* dst = sraw[tb & 1];
    const int t0 = tb << 3;
    const size_t row0 = (size_t)(btbase + t0) * 6144;
#pragma unroll
    for (int j = 0; j < 2; ++j) {
      int c = tid + (j << 8);
      if (c < 292) {
        const void* src;
        if (c < 32)       { src = conv + row0 + (size_t)(c >> 2) * 6144 + xcol + ((c & 3) << 3); }
        else if (c < 160) { int r = c - 32;  src = conv + row0 + (size_t)(r >> 4) * 6144 + 4096 + (g << 7) + ((r & 15) << 3); }
        else if (c < 288) { int r = c - 160; src = conv + row0 + (size_t)(r >> 4) * 6144 + 5120 + (g << 7) + ((r & 15) << 3); }
        else if (c < 290) { src = dt0 + t0 + ((c - 288) << 2); }
        else              { src = dt1 + t0 + ((c - 290) << 2); }
        gload_lds16(src, dst + ((size_t)c << 4));
      }
    }
  };

  stage(0);

  float hs0[8], hs1[8];
  if (EMIT) {
    u16x8 a0 = *(const u16x8*)&hst[hbase + (size_t)p0 * 128 + n0];
    u16x8 a1 = *(const u16x8*)&hst[hbase + (size_t)(p0 + 1) * 128 + n0];
#pragma unroll
    for (int n = 0; n < 8; ++n) { hs0[n] = bf2f(a0[n]); hs1[n] = bf2f(a1[n]); }
  } else {
#pragma unroll
    for (int n = 0; n < 8; ++n) { hs0[n] = 0.f; hs1[n] = 0.f; }
  }
  float dtsum = 0.f;

  for (int tb = 0; tb < 32; ++tb) {
    __syncthreads();
    if (EMIT && tb > 0) {                 // write previous block's y
      const int cur = (tb - 1) & 1;
      const int tprev = btbase + ((tb - 1) << 3);
      const int tt = tid >> 5, p = tid & 31;
      float v = ypart[cur][0][tt][p] + ypart[cur][1][tt][p] +
                ypart[cur][2][tt][p] + ypart[cur][3][tt][p];
      yssm[(size_t)(tprev + tt) * 4096 + xcol + p] = f2bf(v);
    }
    if (tb + 1 < 32) stage(tb + 1);       // prefetch BEFORE compute
    const ushort_t* sbu = (const ushort_t*)sraw[tb & 1];
    const float* sfs = (const float*)(sraw[tb & 1] + 4608);
    const int cur = tb & 1;
#pragma unroll
    for (int tt = 0; tt < 8; ++tt) {
      uint32_t xv = *(const uint32_t*)&sbu[(tt << 5) + p0];
      float x0 = bf2f((ushort_t)xv), x1 = bf2f((ushort_t)(xv >> 16));
      u16x8 bv = *(const u16x8*)&sbu[256 + (tt << 7) + n0];
      float dtv = sfs[tt], ab = sfs[8 + tt];
      if (!EMIT) dtsum += dtv;
      float dtx0 = dtv * x0, dtx1 = dtv * x1;
      if (EMIT) {
        u16x8 cv = *(const u16x8*)&sbu[1280 + (tt << 7) + n0];
        float ys0 = 0.f, ys1 = 0.f;
#pragma unroll
        for (int n = 0; n < 8; ++n) {
          float Bn = bf2f(bv[n]), Cn = bf2f(cv[n]);
          hs0[n] = ab * hs0[n] + dtx0 * Bn; ys0 += hs0[n] * Cn;
          hs1[n] = ab * hs1[n] + dtx1 * Bn; ys1 += hs1[n] * Cn;
        }
        ys0 += __shfl_xor(ys0, 16, 64); ys0 += __shfl_xor(ys0, 32, 64);
        ys1 += __shfl_xor(ys1, 16, 64); ys1 += __shfl_xor(ys1, 32, 64);
        if (wave == 0) { ys0 += Dh * x0; ys1 += Dh * x1; }
        if ((lane >> 4) == 0) {
          f32x2 o; o.x = ys0; o.y = ys1;
          *(f32x2*)&ypart[cur][wave][tt][p0] = o;
        }
      } else {
#pragma unroll
        for (int n = 0; n < 8; ++n) {
          float Bn = bf2f(bv[n]);
          hs0[n] = ab * hs0[n] + dtx0 * Bn;
          hs1[n] = ab * hs1[n] + dtx1 * Bn;
        }
      }
    }
  }
  if (EMIT) {
    __syncthreads();
    const int cur = 31 & 1;
    const int tprev = btbase + (31 << 3);
    const int tt = tid >> 5, p = tid & 31;
    float v = ypart[cur][0][tt][p] + ypart[cur][1][tt][p] +
              ypart[cur][2][tt][p] + ypart[cur][3][tt][p];
    yssm[(size_t)(tprev + tt) * 4096 + xcol + p] = f2bf(v);
  } else {
    u16x8 o0, o1;
#pragma unroll
    for (int n = 0; n < 8; ++n) { o0[n] = f2bf(hs0[n]); o1[n] = f2bf(hs1[n]); }
    *(u16x8*)&hst[hbase + (size_t)p0 * 128 + n0] = o0;
    *(u16x8*)&hst[hbase + (size_t)(p0 + 1) * 128 + n0] = o1;
    if (ph == 0 && tid == 0)
      abprod[((b << 6) + h) * 8 + ck] = expf(Avec[h] * dtsum);
  }
}

// ---------------- combine: prefix over chunk states (in place) ----------------
// grid 256 = (b,h,ph); thread owns 16 contiguous elems of the 32x128 state.
__global__ __launch_bounds__(256) void combine_kernel(ushort_t* __restrict__ hst,
                                                      const float* __restrict__ abprod) {
  const int bid = blockIdx.x;
  const int bh = bid >> 1;
  const int tid = threadIdx.x;
  const size_t base = (size_t)bid * 8 * 4096 + tid * 16;
  float hrun[16];
#pragma unroll
  for (int e = 0; e < 16; ++e) hrun[e] = 0.f;
  for (int c = 0; c < 8; ++c) {
    const size_t p = base + (size_t)c * 4096;
    u16x8 v0 = *(const u16x8*)&hst[p];
    u16x8 v1 = *(const u16x8*)&hst[p + 8];
    float ab = abprod[bh * 8 + c];
    u16x8 w0, w1;
#pragma unroll
    for (int e = 0; e < 8; ++e) { w0[e] = f2bf(hrun[e]); w1[e] = f2bf(hrun[8 + e]); }
    *(u16x8*)&hst[p] = w0;
    *(u16x8*)&hst[p + 8] = w1;
#pragma unroll
    for (int e = 0; e < 8; ++e) {
      hrun[e] = ab * hrun[e] + bf2f(v0[e]);
      hrun[8 + e] = ab * hrun[8 + e] + bf2f(v1[e]);
    }
  }
}

// ---------------- gate * silu + RMSNorm -> bf16 -------------------------------
__global__ __launch_bounds__(256) void norm_kernel(const ushort_t* __restrict__ yssm,
                                                   const ushort_t* __restrict__ gate,
                                                   const float* __restrict__ nw,
                                                   ushort_t* __restrict__ out) {
  const int bt = blockIdx.x;
  const int tid = threadIdx.x;
  const ushort_t* y = yssm + (size_t)bt * 4096;
  const ushort_t* gt = gate + (size_t)bt * 4096;
  float vals[16];
  float ss = 0.f;
#pragma unroll
  for (int j = 0; j < 4; ++j) {
    int o = (tid + j * 256) << 2;
    u16x4 yv = *(const u16x4*)(y + o);
    u16x4 gv = *(const u16x4*)(gt + o);
#pragma unroll
    for (int e = 0; e < 4; ++e) {
      float v = bf2f(yv[e]) * siluf(bf2f(gv[e]));
      vals[j * 4 + e] = v;
      ss += v * v;
    }
  }
#pragma unroll
  for (int m = 1; m <= 32; m <<= 1) ss += __shfl_xor(ss, m, 64);
  __shared__ float red[4];
  if ((tid & 63) == 0) red[tid >> 6] = ss;
  __syncthreads();
  ss = red[0] + red[1] + red[2] + red[3];
  const float sc = rsqrtf(ss * (1.f / 4096.f) + 1e-5f);
#pragma unroll
  for (int j = 0; j < 4; ++j) {
    int o = (tid + j * 256) << 2;
    f32x4 wv = *(const f32x4*)(nw + o);
    u16x4 ov;
    ov.x = f2bf(vals[j * 4 + 0] * sc * wv.x);
    ov.y = f2bf(vals[j * 4 + 1] * sc * wv.y);
    ov.z = f2bf(vals[j * 4 + 2] * sc * wv.z);
    ov.w = f2bf(vals[j * 4 + 3] * sc * wv.w);
    *(u16x4*)(out + (size_t)bt * 4096 + o) = ov;
  }
}

// ------------------------------------------------------------------------------
extern "C" void kernel_launch(void* const* d_in, const int* in_sizes, int n_in,
                              void* d_out, int out_size, void* d_ws, size_t ws_size,
                              hipStream_t stream) {
  const float* hidden  = (const float*)d_in[0];
  const float* w_in    = (const float*)d_in[1];
  const float* conv_w  = (const float*)d_in[2];
  const float* conv_b  = (const float*)d_in[3];
  const float* Avec    = (const float*)d_in[4];
  const float* Dvec    = (const float*)d_in[5];
  const float* dt_bias = (const float*)d_in[6];
  const float* nw      = (const float*)d_in[7];
  const float* w_out   = (const float*)d_in[8];
  float* out = (float*)d_out;

  char* ws = (char*)d_ws;
  // Region map (total 162,693,120 B):
  //  A @0         22,020,096  : Xbf          -> W2bf (after gemm1)
  //  B @22020096  55,738,368  : W1bf         -> conv bf16 (50,331,648) + dtA f32 @+50,331,648 (2,097,152)
  //                                            + abprod f32 @+52,428,800 (4 KB)
  //                                          -> ynorm bf16 @+0 (after scan)
  //  C @77758464  33,554,432  : gate bf16 [4096][4096]
  //  E @111312896 51,380,224  : xbcdt bf16 [4096][6272]
  //                            -> yssm bf16 @+0 (33,554,432) + hst bf16 @+33,554,432 (16,777,216)
  ushort_t* Xbf   = (ushort_t*)(ws);
  ushort_t* W1bf  = (ushort_t*)(ws + 22020096);
  ushort_t* gate  = (ushort_t*)(ws + 77758464);
  ushort_t* xbc   = (ushort_t*)(ws + 111312896);
  ushort_t* W2bf  = Xbf;
  ushort_t* convb = W1bf;
  float*    dtA   = (float*)(ws + 22020096 + 50331648);
  float*    abprod= (float*)(ws + 22020096 + 52428800);
  ushort_t* yssm  = xbc;
  ushort_t* hst   = (ushort_t*)(ws + 111312896 + 33554432);
  ushort_t* ynorm = convb;
  const size_t NEED = 162693120;
  if (NEED > ws_size) {
    fill_kernel<<<4, 256, 0, stream>>>(out, 12345.0f, 1024);   // sentinel: ws too small
    return;
  }

  cvt_bf16_kernel<<<10752, 256, 0, stream>>>(hidden, Xbf, 2752512, 2752512);
  cvt_bf16_kernel<<<27216, 256, 0, stream>>>(w_in, W1bf, 6924288, 6967296);
  gemm_in_kernel<<<dim3(32, 81), 256, 0, stream>>>(Xbf, W1bf, gate, xbc, 2688);
  cvt_bf16_kernel<<<10752, 256, 0, stream>>>(w_out, W2bf, 2752512, 2752512);
  conv_silu_kernel<<<24576, 256, 0, stream>>>(xbc, conv_w, conv_b, convb);
  dt_kernel<<<1024, 256, 0, stream>>>(xbc, dt_bias, Avec, dtA);
  scan_chunk_kernel<0><<<2048, 256, 0, stream>>>(convb, dtA, Dvec, Avec, yssm, hst, abprod);
  combine_kernel<<<256, 256, 0, stream>>>(hst, abprod);
  scan_chunk_kernel<1><<<2048, 256, 0, stream>>>(convb, dtA, Dvec, Avec, yssm, hst, abprod);
  norm_kernel<<<4096, 256, 0, stream>>>(yssm, gate, nw, ynorm);
  gemm_out_kernel<<<dim3(32, 21), 256, 0, stream>>>(ynorm, W2bf, out, 2688, 4096);
}

// Round 6
// 812.908 us; speedup vs baseline: 1.2952x; 1.0600x over previous
//
#include <hip/hip_runtime.h>
#include <stdint.h>

typedef unsigned short ushort_t;
typedef __attribute__((ext_vector_type(4))) float f32x4;
typedef __attribute__((ext_vector_type(2))) float f32x2;
typedef __attribute__((ext_vector_type(8))) __bf16 bf16x8;
typedef __attribute__((ext_vector_type(4))) unsigned short u16x4;
typedef __attribute__((ext_vector_type(8))) unsigned short u16x8;

#define DEV __device__ __forceinline__

// async global->LDS, 16B per lane. HW: dest = wave-uniform base + laneID*16.
DEV void gload_lds16(const void* g, void* l) {
  __builtin_amdgcn_global_load_lds(
      (const __attribute__((address_space(1))) uint32_t*)(uintptr_t)(g),
      (__attribute__((address_space(3))) uint32_t*)(uintptr_t)(l), 16, 0, 0);
}

DEV ushort_t f2bf(float f) {
  union { float f; uint32_t u; } x; x.f = f;
  x.u += 0x7fffu + ((x.u >> 16) & 1u);   // RNE
  return (ushort_t)(x.u >> 16);
}

DEV float bf2f(ushort_t u) {
  union { uint32_t u; float f; } x; x.u = (uint32_t)u << 16; return x.f;
}

DEV float siluf(float x) { return x / (1.f + expf(-x)); }

#define BAR asm volatile("s_barrier" ::: "memory")
#define LGKM0 do { asm volatile("s_waitcnt lgkmcnt(0)" ::: "memory"); \
                   __builtin_amdgcn_sched_barrier(0); } while (0)
#define VMCNT(n) asm volatile("s_waitcnt vmcnt(" #n ")" ::: "memory")

// ---------------- sentinel fill (diagnostic) ----------------------------------
__global__ __launch_bounds__(256) void fill_kernel(float* p, float v, int n) {
  int i = blockIdx.x * 256 + threadIdx.x;
  if (i < n) p[i] = v;
}

// ---------------- f32 -> bf16 convert (with zero tail padding) ---------------
__global__ __launch_bounds__(256) void cvt_bf16_kernel(const float* __restrict__ src,
                                                       ushort_t* __restrict__ dst,
                                                       int n_src4, int n_dst4) {
  int i = blockIdx.x * 256 + threadIdx.x;
  if (i >= n_dst4) return;
  f32x4 v;
  if (i < n_src4) v = *(const f32x4*)(src + (size_t)i * 4);
  else { v.x = 0.f; v.y = 0.f; v.z = 0.f; v.w = 0.f; }
  u16x4 o;
  o.x = f2bf(v.x); o.y = f2bf(v.y); o.z = f2bf(v.z); o.w = f2bf(v.w);
  *(u16x4*)(dst + (size_t)i * 4) = o;
}

// ================= 256x256 8-phase bf16 GEMM (T2+T3+T4+T5) ====================
// C[M,N] = A[M,K] * B[N,K]^T. BM=BN=256, BK=64, 8 waves (2M x 4N), 512 thr.
// LDS 128KB: slot s at s*65536: A 256 rows x 128B, B at +32768.
// Swizzle: element (row, colbyte cb) at LDS lin = row*128 + (cb ^ ((row&7)<<4)).
// Staged linearly (global_load_lds) from inverse-swizzled global source.
// vmcnt DISCIPLINE (R5 NaN lesson): vmcnt is per-wave; a counted wait only
// proves THIS wave's DMA landed. Therefore vmcnt sits at the END of P4/P8
// BEFORE that phase's closing barrier -- after the barrier, every wave has
// passed its own wait, so the whole slot is written before any wave reads it.
// Ledger: end-P4 outstanding = {s1.Ah0,s1.Ah1,s1.Bh0,s1.Bh1,s0'.Ah0} = 10
//   -> vmcnt(2) drains slot1 (8 oldest).  Last iter: vmcnt(0) (8 outstanding).
// end-P8 outstanding = {s0'x4, s1'.Ah0} = 10 -> vmcnt(2) drains slot0'.
// Prologue: stage s0 x4 + s1.Ah0, vmcnt(2), barrier.

DEV void ld_a4(const unsigned char* ab2, int mgofs, int ck0, int ck1, bf16x8 (&af)[4][2]) {
#pragma unroll
  for (int mi = 0; mi < 4; ++mi) {
    const unsigned char* p = ab2 + (mgofs + mi * 16) * 128;
    af[mi][0] = *(const bf16x8*)(p + ck0);
    af[mi][1] = *(const bf16x8*)(p + ck1);
  }
}

DEV void ld_b2(const unsigned char* bb2, int npofs, int ck0, int ck1, bf16x8 (&bf)[2][2]) {
#pragma unroll
  for (int ni = 0; ni < 2; ++ni) {
    const unsigned char* p = bb2 + (npofs + ni * 16) * 128;
    bf[ni][0] = *(const bf16x8*)(p + ck0);
    bf[ni][1] = *(const bf16x8*)(p + ck1);
  }
}

DEV void mm16(f32x4 (&acc)[8][4], const bf16x8 (&af)[4][2], const bf16x8 (&bf)[2][2],
              int mb, int nb) {
  __builtin_amdgcn_s_setprio(1);
#pragma unroll
  for (int mi = 0; mi < 4; ++mi)
#pragma unroll
    for (int ni = 0; ni < 2; ++ni)
#pragma unroll
      for (int kk = 0; kk < 2; ++kk)
        acc[mb + mi][nb + ni] = __builtin_amdgcn_mfma_f32_16x16x32_bf16(
            af[mi][kk], bf[ni][kk], acc[mb + mi][nb + ni], 0, 0, 0);
  __builtin_amdgcn_s_setprio(0);
}

DEV void stage2(const ushort_t* s0, const ushort_t* s1, unsigned char* d) {
  gload_lds16(s0, d);
  gload_lds16(s1, d + 8192);
}

// MODE 0: bf16 out split gate/xbc (GEMM1).  MODE 1: f32 out (GEMM2).
template <int MODE>
__global__ __launch_bounds__(512, 1) void gemm8_kernel(const ushort_t* __restrict__ A,
                                                       const ushort_t* __restrict__ B,
                                                       void* __restrict__ C0,
                                                       void* __restrict__ C1,
                                                       int K, int NB, int NC, int niter) {
  __shared__ __align__(16) unsigned char lds[131072];
  const int tid = threadIdx.x;
  const int l = tid & 63, w = tid >> 6;
  const int wr = w >> 2, wc = w & 3;
  const int lr = l & 15, lk = l >> 4;
  const int xm = (lr & 7) << 4;
  const int ck0 = (lk * 16) ^ xm;
  const int ck1 = (64 + lk * 16) ^ xm;
  const int bm = blockIdx.x, bn = blockIdx.y;

  // staging geometry: dest = half_base + w*1024 + l*16 (linear, lane-prefix).
  // row rr = w*8 + l/8; source col chunk = (l&7)^(l>>3) (inverse of read swz).
  const int rr = (w << 3) + (l >> 3);
  const int cE = ((l & 7) ^ (l >> 3)) << 3;        // col offset in elements
  const int dstoff = w * 1024 + l * 16;

  const ushort_t* sA00 = A + (size_t)(bm * 256 +       rr) * K + cE;
  const ushort_t* sA01 = A + (size_t)(bm * 256 +  64 + rr) * K + cE;
  const ushort_t* sA10 = A + (size_t)(bm * 256 + 128 + rr) * K + cE;
  const ushort_t* sA11 = A + (size_t)(bm * 256 + 192 + rr) * K + cE;
  int rb0 = bn * 256 +       rr; if (rb0 > NB - 1) rb0 = NB - 1;
  int rb1 = bn * 256 +  64 + rr; if (rb1 > NB - 1) rb1 = NB - 1;
  int rb2 = bn * 256 + 128 + rr; if (rb2 > NB - 1) rb2 = NB - 1;
  int rb3 = bn * 256 + 192 + rr; if (rb3 > NB - 1) rb3 = NB - 1;
  const ushort_t* sB00 = B + (size_t)rb0 * K + cE;
  const ushort_t* sB01 = B + (size_t)rb1 * K + cE;
  const ushort_t* sB10 = B + (size_t)rb2 * K + cE;
  const ushort_t* sB11 = B + (size_t)rb3 * K + cE;

  // frag read bases (slot offset added at use)
  const int aoff = wr * 16384 + lr * 128;
  const int boff = 32768 + (wc >> 1) * 16384 + ((wc & 1) * 64 + lr) * 128;

  f32x4 acc[8][4] = {};
  bf16x8 af[4][2], bf[2][2], bg[2][2];

  // prologue: t0 all 4 halves -> slot0; t1.Ah0 -> slot1; drain slot0; barrier
  stage2(sA00, sA01, lds + dstoff);
  stage2(sA10, sA11, lds + 16384 + dstoff);
  stage2(sB00, sB01, lds + 32768 + dstoff);
  stage2(sB10, sB11, lds + 49152 + dstoff);
  stage2(sA00 + 64, sA01 + 64, lds + 65536 + dstoff);
  VMCNT(2);
  BAR;

  auto kpair = [&](int kt0, bool last) {
    const unsigned char* a0 = lds + aoff;
    const unsigned char* b0 = lds + boff;
    const unsigned char* a1 = lds + 65536 + aoff;
    const unsigned char* b1 = lds + 65536 + boff;
    const size_t c1 = (size_t)(kt0 + 1) * 64;
    const size_t c2 = (size_t)(kt0 + 2) * 64;
    const size_t c3 = (size_t)(kt0 + 3) * 64;
    // P1: slot0 q(0,0); stage (t+1).Ah1 -> slot1
    ld_a4(a0, 0, ck0, ck1, af);
    ld_b2(b0, 0, ck0, ck1, bf);
    stage2(sA10 + c1, sA11 + c1, lds + 65536 + 16384 + dstoff);
    BAR; LGKM0; mm16(acc, af, bf, 0, 0); BAR;
    // P2: slot0 q(0,1); stage (t+1).Bh0 -> slot1
    ld_b2(b0, 32, ck0, ck1, bg);
    stage2(sB00 + c1, sB01 + c1, lds + 65536 + 32768 + dstoff);
    BAR; LGKM0; mm16(acc, af, bg, 0, 2); BAR;
    // P3: slot0 q(1,1); stage (t+1).Bh1 -> slot1
    ld_a4(a0, 64, ck0, ck1, af);
    stage2(sB10 + c1, sB11 + c1, lds + 65536 + 49152 + dstoff);
    BAR; LGKM0; mm16(acc, af, bg, 4, 2); BAR;
    // P4: slot0 q(1,0); stage (t+2).Ah0 -> slot0; DRAIN slot1 before barrier
    ld_b2(b0, 0, ck0, ck1, bf);
    if (!last) { stage2(sA00 + c2, sA01 + c2, lds + dstoff); VMCNT(2); }
    else       { VMCNT(0); }
    BAR; LGKM0; mm16(acc, af, bf, 4, 0); BAR;
    // P5: slot1 q(0,0); stage (t+2).Ah1 -> slot0
    ld_a4(a1, 0, ck0, ck1, af);
    ld_b2(b1, 0, ck0, ck1, bf);
    if (!last) stage2(sA10 + c2, sA11 + c2, lds + 16384 + dstoff);
    BAR; LGKM0; mm16(acc, af, bf, 0, 0); BAR;
    // P6: slot1 q(0,1); stage (t+2).Bh0 -> slot0
    ld_b2(b1, 32, ck0, ck1, bg);
    if (!last) stage2(sB00 + c2, sB01 + c2, lds + 32768 + dstoff);
    BAR; LGKM0; mm16(acc, af, bg, 0, 2); BAR;
    // P7: slot1 q(1,1); stage (t+2).Bh1 -> slot0
    ld_a4(a1, 64, ck0, ck1, af);
    if (!last) stage2(sB10 + c2, sB11 + c2, lds + 49152 + dstoff);
    BAR; LGKM0; mm16(acc, af, bg, 4, 2); BAR;
    // P8: slot1 q(1,0); stage (t+3).Ah0 -> slot1; DRAIN slot0(t+2) before bar
    ld_b2(b1, 0, ck0, ck1, bf);
    if (!last) { stage2(sA00 + c3, sA01 + c3, lds + 65536 + dstoff); VMCNT(2); }
    BAR; LGKM0; mm16(acc, af, bf, 4, 0); BAR;
  };

  for (int it = 0; it < niter - 1; ++it) kpair(2 * it, false);
  kpair(2 * (niter - 1), true);

  // epilogue. D layout: col = lane&15, row = (lane>>4)*4 + reg.
  const int crow0 = bm * 256 + wr * 128 + (lk << 2);
  const int ccol0 = bn * 256 + wc * 64 + lr;
  if (MODE == 0) {
    ushort_t* gate = (ushort_t*)C0;
    ushort_t* xbc  = (ushort_t*)C1;
#pragma unroll
    for (int ni = 0; ni < 4; ++ni) {
      const int col = ccol0 + ni * 16;
      if (col < NC) {
        ushort_t* dst; size_t stride;
        if (col < 4096) { dst = gate + col; stride = 4096; }
        else            { dst = xbc + (col - 4096); stride = 6272; }
#pragma unroll
        for (int mi = 0; mi < 8; ++mi)
#pragma unroll
          for (int r = 0; r < 4; ++r)
            dst[(size_t)(crow0 + mi * 16 + r) * stride] = f2bf(acc[mi][ni][r]);
      }
    }
  } else {
    float* o = (float*)C0;
#pragma unroll
    for (int ni = 0; ni < 4; ++ni) {
      const int col = ccol0 + ni * 16;
      if (col < NC) {
#pragma unroll
        for (int mi = 0; mi < 8; ++mi)
#pragma unroll
          for (int r = 0; r < 4; ++r)
            o[(size_t)(crow0 + mi * 16 + r) * NC + col] = acc[mi][ni][r];
      }
    }
  }
}

// ---------------- causal depthwise conv (K=4) + bias + SiLU, bf16 in/out ------
__global__ __launch_bounds__(256) void conv_silu_kernel(const ushort_t* __restrict__ xbc,
                                                        const float* __restrict__ cw,
                                                        const float* __restrict__ cb,
                                                        ushort_t* __restrict__ out) {
  int idx = blockIdx.x * 256 + threadIdx.x;      // 4096*1536
  int c4 = (idx % 1536) << 2;
  int bt = idx / 1536;
  int t = bt & 2047;
  const ushort_t* base = xbc + (size_t)bt * 6272 + c4;
  f32x4 w0 = *(const f32x4*)&cw[(c4 + 0) * 4];
  f32x4 w1 = *(const f32x4*)&cw[(c4 + 1) * 4];
  f32x4 w2 = *(const f32x4*)&cw[(c4 + 2) * 4];
  f32x4 w3 = *(const f32x4*)&cw[(c4 + 3) * 4];
  f32x4 acc = *(const f32x4*)&cb[c4];
#pragma unroll
  for (int i = 0; i < 4; ++i) {
    int dt_ = i - 3;
    if (t + dt_ >= 0) {
      u16x4 xv = *(const u16x4*)(base + (ptrdiff_t)dt_ * 6272);
      acc.x += bf2f(xv.x) * w0[i];
      acc.y += bf2f(xv.y) * w1[i];
      acc.z += bf2f(xv.z) * w2[i];
      acc.w += bf2f(xv.w) * w3[i];
    }
  }
  u16x4 o;
  o.x = f2bf(siluf(acc.x)); o.y = f2bf(siluf(acc.y));
  o.z = f2bf(siluf(acc.z)); o.w = f2bf(siluf(acc.w));
  *(u16x4*)(out + (size_t)bt * 6144 + c4) = o;
}

// ---------------- dt: softplus + exp(A*dt), layout [H][2][BT] f32 -------------
__global__ __launch_bounds__(256) void dt_kernel(const ushort_t* __restrict__ xbc,
                                                 const float* __restrict__ dt_bias,
                                                 const float* __restrict__ Avec,
                                                 float* __restrict__ dtA) {
  int idx = blockIdx.x * 256 + threadIdx.x;      // 64*4096
  int h = idx >> 12, bt = idx & 4095;
  float v = bf2f(xbc[(size_t)bt * 6272 + 6144 + h]) + dt_bias[h];
  float sp = fmaxf(v, 0.f) + log1pf(expf(-fabsf(v)));
  float ab = expf(Avec[h] * sp);
  dtA[(h << 13) + bt] = sp;
  dtA[(h << 13) + 4096 + bt] = ab;
}

// ---------------- chunked selective scan ---------------------------------------
// grid 2048 = B(2) x H(64) x Phalf(2) x Chunk(8), chunk = 256 steps.
// EMIT=0: scan from zero init, write final chunk state (bf16) + abprod.
// EMIT=1: scan from combined init, emit y. stage() identical for both EMIT
// (global_load_lds active lanes must form a prefix from lane 0 — R3 lesson).
template <int EMIT>
__global__ __launch_bounds__(256) void scan_chunk_kernel(const ushort_t* __restrict__ conv,
                                                         const float* __restrict__ dtA,
                                                         const float* __restrict__ Dvec,
                                                         const float* __restrict__ Avec,
                                                         ushort_t* __restrict__ yssm,
                                                         ushort_t* __restrict__ hst,
                                                         float* __restrict__ abprod) {
  const int bid = blockIdx.x;
  const int ck = bid & 7;
  const int ph = (bid >> 3) & 1;
  const int h = (bid >> 4) & 63;
  const int b = bid >> 10;
  const int g = h >> 3;
  const int tid = threadIdx.x;
  const int lane = tid & 63;
  const int wave = tid >> 6;
  const int pg = tid & 15, ng = tid >> 4;
  const int p0 = pg << 1, n0 = ng << 3;

  __shared__ __align__(16) unsigned char sraw[2][4672];
  __shared__ __align__(16) float ypart[2][4][8][32];

  const int btbase = (b << 11) + (ck << 8);
  const float* dt0 = dtA + (h << 13) + btbase;
  const float* dt1 = dt0 + 4096;
  const float Dh = Dvec[h];
  const int xcol = (h << 6) + (ph << 5);
  const size_t hbase = (size_t)bid * 4096;

  auto stage = [&](int tb) {
    unsigned char* dst = sraw[tb & 1];
    const int t0 = tb << 3;
    const size_t row0 = (size_t)(btbase + t0) * 6144;
#pragma unroll
    for (int j = 0; j < 2; ++j) {
      int c = tid + (j << 8);
      if (c < 292) {
        const void* src;
        if (c < 32)       { src = conv + row0 + (size_t)(c >> 2) * 6144 + xcol + ((c & 3) << 3); }
        else if (c < 160) { int r = c - 32;  src = conv + row0 + (size_t)(r >> 4) * 6144 + 4096 + (g << 7) + ((r & 15) << 3); }
        else if (c < 288) { int r = c - 160; src = conv + row0 + (size_t)(r >> 4) * 6144 + 5120 + (g << 7) + ((r & 15) << 3); }
        else if (c < 290) { src = dt0 + t0 + ((c - 288) << 2); }
        else              { src = dt1 + t0 + ((c - 290) << 2); }
        gload_lds16(src, dst + ((size_t)c << 4));
      }
    }
  };

  stage(0);

  float hs0[8], hs1[8];
  if (EMIT) {
    u16x8 a0 = *(const u16x8*)&hst[hbase + (size_t)p0 * 128 + n0];
    u16x8 a1 = *(const u16x8*)&hst[hbase + (size_t)(p0 + 1) * 128 + n0];
#pragma unroll
    for (int n = 0; n < 8; ++n) { hs0[n] = bf2f(a0[n]); hs1[n] = bf2f(a1[n]); }
  } else {
#pragma unroll
    for (int n = 0; n < 8; ++n) { hs0[n] = 0.f; hs1[n] = 0.f; }
  }
  float dtsum = 0.f;

  for (int tb = 0; tb < 32; ++tb) {
    __syncthreads();
    if (EMIT && tb > 0) {
      const int cur = (tb - 1) & 1;
      const int tprev = btbase + ((tb - 1) << 3);
      const int tt = tid >> 5, p = tid & 31;
      float v = ypart[cur][0][tt][p] + ypart[cur][1][tt][p] +
                ypart[cur][2][tt][p] + ypart[cur][3][tt][p];
      yssm[(size_t)(tprev + tt) * 4096 + xcol + p] = f2bf(v);
    }
    if (tb + 1 < 32) stage(tb + 1);
    const ushort_t* sbu = (const ushort_t*)sraw[tb & 1];
    const float* sfs = (const float*)(sraw[tb & 1] + 4608);
    const int cur = tb & 1;
#pragma unroll
    for (int tt = 0; tt < 8; ++tt) {
      uint32_t xv = *(const uint32_t*)&sbu[(tt << 5) + p0];
      float x0 = bf2f((ushort_t)xv), x1 = bf2f((ushort_t)(xv >> 16));
      u16x8 bv = *(const u16x8*)&sbu[256 + (tt << 7) + n0];
      float dtv = sfs[tt], ab = sfs[8 + tt];
      if (!EMIT) dtsum += dtv;
      float dtx0 = dtv * x0, dtx1 = dtv * x1;
      if (EMIT) {
        u16x8 cv = *(const u16x8*)&sbu[1280 + (tt << 7) + n0];
        float ys0 = 0.f, ys1 = 0.f;
#pragma unroll
        for (int n = 0; n < 8; ++n) {
          float Bn = bf2f(bv[n]), Cn = bf2f(cv[n]);
          hs0[n] = ab * hs0[n] + dtx0 * Bn; ys0 += hs0[n] * Cn;
          hs1[n] = ab * hs1[n] + dtx1 * Bn; ys1 += hs1[n] * Cn;
        }
        ys0 += __shfl_xor(ys0, 16, 64); ys0 += __shfl_xor(ys0, 32, 64);
        ys1 += __shfl_xor(ys1, 16, 64); ys1 += __shfl_xor(ys1, 32, 64);
        if (wave == 0) { ys0 += Dh * x0; ys1 += Dh * x1; }
        if ((lane >> 4) == 0) {
          f32x2 o; o.x = ys0; o.y = ys1;
          *(f32x2*)&ypart[cur][wave][tt][p0] = o;
        }
      } else {
#pragma unroll
        for (int n = 0; n < 8; ++n) {
          float Bn = bf2f(bv[n]);
          hs0[n] = ab * hs0[n] + dtx0 * Bn;
          hs1[n] = ab * hs1[n] + dtx1 * Bn;
        }
      }
    }
  }
  if (EMIT) {
    __syncthreads();
    const int cur = 31 & 1;
    const int tprev = btbase + (31 << 3);
    const int tt = tid >> 5, p = tid & 31;
    float v = ypart[cur][0][tt][p] + ypart[cur][1][tt][p] +
              ypart[cur][2][tt][p] + ypart[cur][3][tt][p];
    yssm[(size_t)(tprev + tt) * 4096 + xcol + p] = f2bf(v);
  } else {
    u16x8 o0, o1;
#pragma unroll
    for (int n = 0; n < 8; ++n) { o0[n] = f2bf(hs0[n]); o1[n] = f2bf(hs1[n]); }
    *(u16x8*)&hst[hbase + (size_t)p0 * 128 + n0] = o0;
    *(u16x8*)&hst[hbase + (size_t)(p0 + 1) * 128 + n0] = o1;
    if (ph == 0 && tid == 0)
      abprod[((b << 6) + h) * 8 + ck] = expf(Avec[h] * dtsum);
  }
}

// ---------------- combine: prefix over chunk states (in place) ----------------
__global__ __launch_bounds__(256) void combine_kernel(ushort_t* __restrict__ hst,
                                                      const float* __restrict__ abprod) {
  const int bid = blockIdx.x;
  const int bh = bid >> 1;
  const int tid = threadIdx.x;
  const size_t base = (size_t)bid * 8 * 4096 + tid * 16;
  float hrun[16];
#pragma unroll
  for (int e = 0; e < 16; ++e) hrun[e] = 0.f;
  for (int c = 0; c < 8; ++c) {
    const size_t p = base + (size_t)c * 4096;
    u16x8 v0 = *(const u16x8*)&hst[p];
    u16x8 v1 = *(const u16x8*)&hst[p + 8];
    float ab = abprod[bh * 8 + c];
    u16x8 w0, w1;
#pragma unroll
    for (int e = 0; e < 8; ++e) { w0[e] = f2bf(hrun[e]); w1[e] = f2bf(hrun[8 + e]); }
    *(u16x8*)&hst[p] = w0;
    *(u16x8*)&hst[p + 8] = w1;
#pragma unroll
    for (int e = 0; e < 8; ++e) {
      hrun[e] = ab * hrun[e] + bf2f(v0[e]);
      hrun[8 + e] = ab * hrun[8 + e] + bf2f(v1[e]);
    }
  }
}

// ---------------- gate * silu + RMSNorm -> bf16 -------------------------------
__global__ __launch_bounds__(256) void norm_kernel(const ushort_t* __restrict__ yssm,
                                                   const ushort_t* __restrict__ gate,
                                                   const float* __restrict__ nw,
                                                   ushort_t* __restrict__ out) {
  const int bt = blockIdx.x;
  const int tid = threadIdx.x;
  const ushort_t* y = yssm + (size_t)bt * 4096;
  const ushort_t* gt = gate + (size_t)bt * 4096;
  float vals[16];
  float ss = 0.f;
#pragma unroll
  for (int j = 0; j < 4; ++j) {
    int o = (tid + j * 256) << 2;
    u16x4 yv = *(const u16x4*)(y + o);
    u16x4 gv = *(const u16x4*)(gt + o);
#pragma unroll
    for (int e = 0; e < 4; ++e) {
      float v = bf2f(yv[e]) * siluf(bf2f(gv[e]));
      vals[j * 4 + e] = v;
      ss += v * v;
    }
  }
#pragma unroll
  for (int m = 1; m <= 32; m <<= 1) ss += __shfl_xor(ss, m, 64);
  __shared__ float red[4];
  if ((tid & 63) == 0) red[tid >> 6] = ss;
  __syncthreads();
  ss = red[0] + red[1] + red[2] + red[3];
  const float sc = rsqrtf(ss * (1.f / 4096.f) + 1e-5f);
#pragma unroll
  for (int j = 0; j < 4; ++j) {
    int o = (tid + j * 256) << 2;
    f32x4 wv = *(const f32x4*)(nw + o);
    u16x4 ov;
    ov.x = f2bf(vals[j * 4 + 0] * sc * wv.x);
    ov.y = f2bf(vals[j * 4 + 1] * sc * wv.y);
    ov.z = f2bf(vals[j * 4 + 2] * sc * wv.z);
    ov.w = f2bf(vals[j * 4 + 3] * sc * wv.w);
    *(u16x4*)(out + (size_t)bt * 4096 + o) = ov;
  }
}

// ------------------------------------------------------------------------------
extern "C" void kernel_launch(void* const* d_in, const int* in_sizes, int n_in,
                              void* d_out, int out_size, void* d_ws, size_t ws_size,
                              hipStream_t stream) {
  const float* hidden  = (const float*)d_in[0];
  const float* w_in    = (const float*)d_in[1];
  const float* conv_w  = (const float*)d_in[2];
  const float* conv_b  = (const float*)d_in[3];
  const float* Avec    = (const float*)d_in[4];
  const float* Dvec    = (const float*)d_in[5];
  const float* dt_bias = (const float*)d_in[6];
  const float* nw      = (const float*)d_in[7];
  const float* w_out   = (const float*)d_in[8];
  float* out = (float*)d_out;

  char* ws = (char*)d_ws;
  // Region map (total 162,693,120 B) — unchanged from R4.
  ushort_t* Xbf   = (ushort_t*)(ws);
  ushort_t* W1bf  = (ushort_t*)(ws + 22020096);
  ushort_t* gate  = (ushort_t*)(ws + 77758464);
  ushort_t* xbc   = (ushort_t*)(ws + 111312896);
  ushort_t* W2bf  = Xbf;
  ushort_t* convb = W1bf;
  float*    dtA   = (float*)(ws + 22020096 + 50331648);
  float*    abprod= (float*)(ws + 22020096 + 52428800);
  ushort_t* yssm  = xbc;
  ushort_t* hst   = (ushort_t*)(ws + 111312896 + 33554432);
  ushort_t* ynorm = convb;
  const size_t NEED = 162693120;
  if (NEED > ws_size) {
    fill_kernel<<<4, 256, 0, stream>>>(out, 12345.0f, 1024);   // sentinel: ws too small
    return;
  }

  cvt_bf16_kernel<<<10752, 256, 0, stream>>>(hidden, Xbf, 2752512, 2752512);
  cvt_bf16_kernel<<<27216, 256, 0, stream>>>(w_in, W1bf, 6924288, 6967296);
  gemm8_kernel<0><<<dim3(16, 41), 512, 0, stream>>>(Xbf, W1bf, gate, xbc,
                                                    2688, 10368, 10304, 21);
  cvt_bf16_kernel<<<10752, 256, 0, stream>>>(w_out, W2bf, 2752512, 2752512);
  conv_silu_kernel<<<24576, 256, 0, stream>>>(xbc, conv_w, conv_b, convb);
  dt_kernel<<<1024, 256, 0, stream>>>(xbc, dt_bias, Avec, dtA);
  scan_chunk_kernel<0><<<2048, 256, 0, stream>>>(convb, dtA, Dvec, Avec, yssm, hst, abprod);
  combine_kernel<<<256, 256, 0, stream>>>(hst, abprod);
  scan_chunk_kernel<1><<<2048, 256, 0, stream>>>(convb, dtA, Dvec, Avec, yssm, hst, abprod);
  norm_kernel<<<4096, 256, 0, stream>>>(yssm, gate, nw, ynorm);
  gemm8_kernel<1><<<dim3(16, 11), 512, 0, stream>>>(ynorm, W2bf, out, nullptr,
                                                    4096, 2688, 2688, 32);
}

// Round 7
// 789.941 us; speedup vs baseline: 1.3329x; 1.0291x over previous
//
#include <hip/hip_runtime.h>
#include <stdint.h>

typedef unsigned short ushort_t;
typedef __attribute__((ext_vector_type(4))) float f32x4;
typedef __attribute__((ext_vector_type(2))) float f32x2;
typedef __attribute__((ext_vector_type(8))) __bf16 bf16x8;
typedef __attribute__((ext_vector_type(4))) unsigned short u16x4;
typedef __attribute__((ext_vector_type(8))) unsigned short u16x8;

#define DEV __device__ __forceinline__

// async global->LDS, 16B per lane. HW: dest = wave-uniform base + laneID*16.
DEV void gload_lds16(const void* g, void* l) {
  __builtin_amdgcn_global_load_lds(
      (const __attribute__((address_space(1))) uint32_t*)(uintptr_t)(g),
      (__attribute__((address_space(3))) uint32_t*)(uintptr_t)(l), 16, 0, 0);
}

DEV ushort_t f2bf(float f) {
  union { float f; uint32_t u; } x; x.f = f;
  x.u += 0x7fffu + ((x.u >> 16) & 1u);   // RNE
  return (ushort_t)(x.u >> 16);
}

DEV float bf2f(ushort_t u) {
  union { uint32_t u; float f; } x; x.u = (uint32_t)u << 16; return x.f;
}

DEV float siluf(float x) { return x / (1.f + expf(-x)); }

#define BAR asm volatile("s_barrier" ::: "memory")
#define LGKM0 do { asm volatile("s_waitcnt lgkmcnt(0)" ::: "memory"); \
                   __builtin_amdgcn_sched_barrier(0); } while (0)
#define VMCNT(n) asm volatile("s_waitcnt vmcnt(" #n ")" ::: "memory")

// ---------------- sentinel fill (diagnostic) ----------------------------------
__global__ __launch_bounds__(256) void fill_kernel(float* p, float v, int n) {
  int i = blockIdx.x * 256 + threadIdx.x;
  if (i < n) p[i] = v;
}

// ---------------- f32 -> bf16 convert (with zero tail padding) ---------------
__global__ __launch_bounds__(256) void cvt_bf16_kernel(const float* __restrict__ src,
                                                       ushort_t* __restrict__ dst,
                                                       int n_src4, int n_dst4) {
  int i = blockIdx.x * 256 + threadIdx.x;
  if (i >= n_dst4) return;
  f32x4 v;
  if (i < n_src4) v = *(const f32x4*)(src + (size_t)i * 4);
  else { v.x = 0.f; v.y = 0.f; v.z = 0.f; v.w = 0.f; }
  u16x4 o;
  o.x = f2bf(v.x); o.y = f2bf(v.y); o.z = f2bf(v.z); o.w = f2bf(v.w);
  *(u16x4*)(dst + (size_t)i * 4) = o;
}

// ================= 256x256 8-phase bf16 GEMM (T2+T3+T4+T5) ====================
// (unchanged from R6 PASS — see R5/R6 notes for vmcnt discipline)
DEV void ld_a4(const unsigned char* ab2, int mgofs, int ck0, int ck1, bf16x8 (&af)[4][2]) {
#pragma unroll
  for (int mi = 0; mi < 4; ++mi) {
    const unsigned char* p = ab2 + (mgofs + mi * 16) * 128;
    af[mi][0] = *(const bf16x8*)(p + ck0);
    af[mi][1] = *(const bf16x8*)(p + ck1);
  }
}

DEV void ld_b2(const unsigned char* bb2, int npofs, int ck0, int ck1, bf16x8 (&bf)[2][2]) {
#pragma unroll
  for (int ni = 0; ni < 2; ++ni) {
    const unsigned char* p = bb2 + (npofs + ni * 16) * 128;
    bf[ni][0] = *(const bf16x8*)(p + ck0);
    bf[ni][1] = *(const bf16x8*)(p + ck1);
  }
}

DEV void mm16(f32x4 (&acc)[8][4], const bf16x8 (&af)[4][2], const bf16x8 (&bf)[2][2],
              int mb, int nb) {
  __builtin_amdgcn_s_setprio(1);
#pragma unroll
  for (int mi = 0; mi < 4; ++mi)
#pragma unroll
    for (int ni = 0; ni < 2; ++ni)
#pragma unroll
      for (int kk = 0; kk < 2; ++kk)
        acc[mb + mi][nb + ni] = __builtin_amdgcn_mfma_f32_16x16x32_bf16(
            af[mi][kk], bf[ni][kk], acc[mb + mi][nb + ni], 0, 0, 0);
  __builtin_amdgcn_s_setprio(0);
}

DEV void stage2(const ushort_t* s0, const ushort_t* s1, unsigned char* d) {
  gload_lds16(s0, d);
  gload_lds16(s1, d + 8192);
}

template <int MODE>
__global__ __launch_bounds__(512, 1) void gemm8_kernel(const ushort_t* __restrict__ A,
                                                       const ushort_t* __restrict__ B,
                                                       void* __restrict__ C0,
                                                       void* __restrict__ C1,
                                                       int K, int NB, int NC, int niter) {
  __shared__ __align__(16) unsigned char lds[131072];
  const int tid = threadIdx.x;
  const int l = tid & 63, w = tid >> 6;
  const int wr = w >> 2, wc = w & 3;
  const int lr = l & 15, lk = l >> 4;
  const int xm = (lr & 7) << 4;
  const int ck0 = (lk * 16) ^ xm;
  const int ck1 = (64 + lk * 16) ^ xm;
  const int bm = blockIdx.x, bn = blockIdx.y;

  const int rr = (w << 3) + (l >> 3);
  const int cE = ((l & 7) ^ (l >> 3)) << 3;
  const int dstoff = w * 1024 + l * 16;

  const ushort_t* sA00 = A + (size_t)(bm * 256 +       rr) * K + cE;
  const ushort_t* sA01 = A + (size_t)(bm * 256 +  64 + rr) * K + cE;
  const ushort_t* sA10 = A + (size_t)(bm * 256 + 128 + rr) * K + cE;
  const ushort_t* sA11 = A + (size_t)(bm * 256 + 192 + rr) * K + cE;
  int rb0 = bn * 256 +       rr; if (rb0 > NB - 1) rb0 = NB - 1;
  int rb1 = bn * 256 +  64 + rr; if (rb1 > NB - 1) rb1 = NB - 1;
  int rb2 = bn * 256 + 128 + rr; if (rb2 > NB - 1) rb2 = NB - 1;
  int rb3 = bn * 256 + 192 + rr; if (rb3 > NB - 1) rb3 = NB - 1;
  const ushort_t* sB00 = B + (size_t)rb0 * K + cE;
  const ushort_t* sB01 = B + (size_t)rb1 * K + cE;
  const ushort_t* sB10 = B + (size_t)rb2 * K + cE;
  const ushort_t* sB11 = B + (size_t)rb3 * K + cE;

  const int aoff = wr * 16384 + lr * 128;
  const int boff = 32768 + (wc >> 1) * 16384 + ((wc & 1) * 64 + lr) * 128;

  f32x4 acc[8][4] = {};
  bf16x8 af[4][2], bf[2][2], bg[2][2];

  stage2(sA00, sA01, lds + dstoff);
  stage2(sA10, sA11, lds + 16384 + dstoff);
  stage2(sB00, sB01, lds + 32768 + dstoff);
  stage2(sB10, sB11, lds + 49152 + dstoff);
  stage2(sA00 + 64, sA01 + 64, lds + 65536 + dstoff);
  VMCNT(2);
  BAR;

  auto kpair = [&](int kt0, bool last) {
    const unsigned char* a0 = lds + aoff;
    const unsigned char* b0 = lds + boff;
    const unsigned char* a1 = lds + 65536 + aoff;
    const unsigned char* b1 = lds + 65536 + boff;
    const size_t c1 = (size_t)(kt0 + 1) * 64;
    const size_t c2 = (size_t)(kt0 + 2) * 64;
    const size_t c3 = (size_t)(kt0 + 3) * 64;
    ld_a4(a0, 0, ck0, ck1, af);
    ld_b2(b0, 0, ck0, ck1, bf);
    stage2(sA10 + c1, sA11 + c1, lds + 65536 + 16384 + dstoff);
    BAR; LGKM0; mm16(acc, af, bf, 0, 0); BAR;
    ld_b2(b0, 32, ck0, ck1, bg);
    stage2(sB00 + c1, sB01 + c1, lds + 65536 + 32768 + dstoff);
    BAR; LGKM0; mm16(acc, af, bg, 0, 2); BAR;
    ld_a4(a0, 64, ck0, ck1, af);
    stage2(sB10 + c1, sB11 + c1, lds + 65536 + 49152 + dstoff);
    BAR; LGKM0; mm16(acc, af, bg, 4, 2); BAR;
    ld_b2(b0, 0, ck0, ck1, bf);
    if (!last) { stage2(sA00 + c2, sA01 + c2, lds + dstoff); VMCNT(2); }
    else       { VMCNT(0); }
    BAR; LGKM0; mm16(acc, af, bf, 4, 0); BAR;
    ld_a4(a1, 0, ck0, ck1, af);
    ld_b2(b1, 0, ck0, ck1, bf);
    if (!last) stage2(sA10 + c2, sA11 + c2, lds + 16384 + dstoff);
    BAR; LGKM0; mm16(acc, af, bf, 0, 0); BAR;
    ld_b2(b1, 32, ck0, ck1, bg);
    if (!last) stage2(sB00 + c2, sB01 + c2, lds + 32768 + dstoff);
    BAR; LGKM0; mm16(acc, af, bg, 0, 2); BAR;
    ld_a4(a1, 64, ck0, ck1, af);
    if (!last) stage2(sB10 + c2, sB11 + c2, lds + 49152 + dstoff);
    BAR; LGKM0; mm16(acc, af, bg, 4, 2); BAR;
    ld_b2(b1, 0, ck0, ck1, bf);
    if (!last) { stage2(sA00 + c3, sA01 + c3, lds + 65536 + dstoff); VMCNT(2); }
    BAR; LGKM0; mm16(acc, af, bf, 4, 0); BAR;
  };

  for (int it = 0; it < niter - 1; ++it) kpair(2 * it, false);
  kpair(2 * (niter - 1), true);

  const int crow0 = bm * 256 + wr * 128 + (lk << 2);
  const int ccol0 = bn * 256 + wc * 64 + lr;
  if (MODE == 0) {
    ushort_t* gate = (ushort_t*)C0;
    ushort_t* xbc  = (ushort_t*)C1;
#pragma unroll
    for (int ni = 0; ni < 4; ++ni) {
      const int col = ccol0 + ni * 16;
      if (col < NC) {
        ushort_t* dst; size_t stride;
        if (col < 4096) { dst = gate + col; stride = 4096; }
        else            { dst = xbc + (col - 4096); stride = 6272; }
#pragma unroll
        for (int mi = 0; mi < 8; ++mi)
#pragma unroll
          for (int r = 0; r < 4; ++r)
            dst[(size_t)(crow0 + mi * 16 + r) * stride] = f2bf(acc[mi][ni][r]);
      }
    }
  } else {
    float* o = (float*)C0;
#pragma unroll
    for (int ni = 0; ni < 4; ++ni) {
      const int col = ccol0 + ni * 16;
      if (col < NC) {
#pragma unroll
        for (int mi = 0; mi < 8; ++mi)
#pragma unroll
          for (int r = 0; r < 4; ++r)
            o[(size_t)(crow0 + mi * 16 + r) * NC + col] = acc[mi][ni][r];
      }
    }
  }
}

// ---------------- causal depthwise conv (K=4) + bias + SiLU, bf16 in/out ------
__global__ __launch_bounds__(256) void conv_silu_kernel(const ushort_t* __restrict__ xbc,
                                                        const float* __restrict__ cw,
                                                        const float* __restrict__ cb,
                                                        ushort_t* __restrict__ out) {
  int idx = blockIdx.x * 256 + threadIdx.x;      // 4096*1536
  int c4 = (idx % 1536) << 2;
  int bt = idx / 1536;
  int t = bt & 2047;
  const ushort_t* base = xbc + (size_t)bt * 6272 + c4;
  f32x4 w0 = *(const f32x4*)&cw[(c4 + 0) * 4];
  f32x4 w1 = *(const f32x4*)&cw[(c4 + 1) * 4];
  f32x4 w2 = *(const f32x4*)&cw[(c4 + 2) * 4];
  f32x4 w3 = *(const f32x4*)&cw[(c4 + 3) * 4];
  f32x4 acc = *(const f32x4*)&cb[c4];
#pragma unroll
  for (int i = 0; i < 4; ++i) {
    int dt_ = i - 3;
    if (t + dt_ >= 0) {
      u16x4 xv = *(const u16x4*)(base + (ptrdiff_t)dt_ * 6272);
      acc.x += bf2f(xv.x) * w0[i];
      acc.y += bf2f(xv.y) * w1[i];
      acc.z += bf2f(xv.z) * w2[i];
      acc.w += bf2f(xv.w) * w3[i];
    }
  }
  u16x4 o;
  o.x = f2bf(siluf(acc.x)); o.y = f2bf(siluf(acc.y));
  o.z = f2bf(siluf(acc.z)); o.w = f2bf(siluf(acc.w));
  *(u16x4*)(out + (size_t)bt * 6144 + c4) = o;
}

// ---------------- dt: softplus + exp(A*dt), layout [H][2][BT] f32 -------------
__global__ __launch_bounds__(256) void dt_kernel(const ushort_t* __restrict__ xbc,
                                                 const float* __restrict__ dt_bias,
                                                 const float* __restrict__ Avec,
                                                 float* __restrict__ dtA) {
  int idx = blockIdx.x * 256 + threadIdx.x;      // 64*4096
  int h = idx >> 12, bt = idx & 4095;
  float v = bf2f(xbc[(size_t)bt * 6272 + 6144 + h]) + dt_bias[h];
  float sp = fmaxf(v, 0.f) + log1pf(expf(-fabsf(v)));
  float ab = expf(Avec[h] * sp);
  dtA[(h << 13) + bt] = sp;
  dtA[(h << 13) + 4096 + bt] = ab;
}

// ---------------- scan pass 1: zero-init, emit y, write final state ----------
// grid 2048 = B(2) x H(64) x Phalf(2) x Chunk(8), chunk = 256 steps.
// y[t] written here EXCLUDES the inter-chunk contribution; correct_kernel adds
// pd[t] * (C_t . H_init) afterwards (linearity of the recurrence in h).
__global__ __launch_bounds__(256) void scan_pass1_kernel(const ushort_t* __restrict__ conv,
                                                         const float* __restrict__ dtA,
                                                         const float* __restrict__ Dvec,
                                                         const float* __restrict__ Avec,
                                                         ushort_t* __restrict__ yssm,
                                                         ushort_t* __restrict__ hst,
                                                         float* __restrict__ abprod) {
  const int bid = blockIdx.x;
  const int ck = bid & 7;
  const int ph = (bid >> 3) & 1;
  const int h = (bid >> 4) & 63;
  const int b = bid >> 10;
  const int g = h >> 3;
  const int tid = threadIdx.x;
  const int lane = tid & 63;
  const int wave = tid >> 6;
  const int pg = tid & 15, ng = tid >> 4;
  const int p0 = pg << 1, n0 = ng << 3;

  __shared__ __align__(16) unsigned char sraw[2][4672];
  __shared__ __align__(16) float ypart[2][4][8][32];

  const int btbase = (b << 11) + (ck << 8);
  const float* dt0 = dtA + (h << 13) + btbase;
  const float* dt1 = dt0 + 4096;
  const float Dh = Dvec[h];
  const int xcol = (h << 6) + (ph << 5);
  const size_t hbase = (size_t)bid * 4096;

  auto stage = [&](int tb) {
    unsigned char* dst = sraw[tb & 1];
    const int t0 = tb << 3;
    const size_t row0 = (size_t)(btbase + t0) * 6144;
#pragma unroll
    for (int j = 0; j < 2; ++j) {
      int c = tid + (j << 8);
      if (c < 292) {
        const void* src;
        if (c < 32)       { src = conv + row0 + (size_t)(c >> 2) * 6144 + xcol + ((c & 3) << 3); }
        else if (c < 160) { int r = c - 32;  src = conv + row0 + (size_t)(r >> 4) * 6144 + 4096 + (g << 7) + ((r & 15) << 3); }
        else if (c < 288) { int r = c - 160; src = conv + row0 + (size_t)(r >> 4) * 6144 + 5120 + (g << 7) + ((r & 15) << 3); }
        else if (c < 290) { src = dt0 + t0 + ((c - 288) << 2); }
        else              { src = dt1 + t0 + ((c - 290) << 2); }
        gload_lds16(src, dst + ((size_t)c << 4));
      }
    }
  };

  stage(0);

  float hs0[8], hs1[8];
#pragma unroll
  for (int n = 0; n < 8; ++n) { hs0[n] = 0.f; hs1[n] = 0.f; }
  float dtsum = 0.f;

  for (int tb = 0; tb < 32; ++tb) {
    __syncthreads();
    if (tb > 0) {
      const int cur = (tb - 1) & 1;
      const int tprev = btbase + ((tb - 1) << 3);
      const int tt = tid >> 5, p = tid & 31;
      float v = ypart[cur][0][tt][p] + ypart[cur][1][tt][p] +
                ypart[cur][2][tt][p] + ypart[cur][3][tt][p];
      yssm[(size_t)(tprev + tt) * 4096 + xcol + p] = f2bf(v);
    }
    if (tb + 1 < 32) stage(tb + 1);
    const ushort_t* sbu = (const ushort_t*)sraw[tb & 1];
    const float* sfs = (const float*)(sraw[tb & 1] + 4608);
    const int cur = tb & 1;
#pragma unroll
    for (int tt = 0; tt < 8; ++tt) {
      uint32_t xv = *(const uint32_t*)&sbu[(tt << 5) + p0];
      float x0 = bf2f((ushort_t)xv), x1 = bf2f((ushort_t)(xv >> 16));
      u16x8 bv = *(const u16x8*)&sbu[256 + (tt << 7) + n0];
      u16x8 cv = *(const u16x8*)&sbu[1280 + (tt << 7) + n0];
      float dtv = sfs[tt], ab = sfs[8 + tt];
      dtsum += dtv;
      float dtx0 = dtv * x0, dtx1 = dtv * x1;
      float ys0 = 0.f, ys1 = 0.f;
#pragma unroll
      for (int n = 0; n < 8; ++n) {
        float Bn = bf2f(bv[n]), Cn = bf2f(cv[n]);
        hs0[n] = ab * hs0[n] + dtx0 * Bn; ys0 += hs0[n] * Cn;
        hs1[n] = ab * hs1[n] + dtx1 * Bn; ys1 += hs1[n] * Cn;
      }
      ys0 += __shfl_xor(ys0, 16, 64); ys0 += __shfl_xor(ys0, 32, 64);
      ys1 += __shfl_xor(ys1, 16, 64); ys1 += __shfl_xor(ys1, 32, 64);
      if (wave == 0) { ys0 += Dh * x0; ys1 += Dh * x1; }
      if ((lane >> 4) == 0) {
        f32x2 o; o.x = ys0; o.y = ys1;
        *(f32x2*)&ypart[cur][wave][tt][p0] = o;
      }
    }
  }
  // final chunk state (zero-init scan) + abprod
  {
    u16x8 o0, o1;
#pragma unroll
    for (int n = 0; n < 8; ++n) { o0[n] = f2bf(hs0[n]); o1[n] = f2bf(hs1[n]); }
    *(u16x8*)&hst[hbase + (size_t)p0 * 128 + n0] = o0;
    *(u16x8*)&hst[hbase + (size_t)(p0 + 1) * 128 + n0] = o1;
    if (ph == 0 && tid == 0)
      abprod[((b << 6) + h) * 8 + ck] = expf(Avec[h] * dtsum);
  }
  __syncthreads();
  {
    const int cur = 31 & 1;
    const int tprev = btbase + (31 << 3);
    const int tt = tid >> 5, p = tid & 31;
    float v = ypart[cur][0][tt][p] + ypart[cur][1][tt][p] +
              ypart[cur][2][tt][p] + ypart[cur][3][tt][p];
    yssm[(size_t)(tprev + tt) * 4096 + xcol + p] = f2bf(v);
  }
}

// ---------------- combine: prefix over chunk states (in place) ----------------
__global__ __launch_bounds__(256) void combine_kernel(ushort_t* __restrict__ hst,
                                                      const float* __restrict__ abprod) {
  const int bid = blockIdx.x;
  const int bh = bid >> 1;
  const int tid = threadIdx.x;
  const size_t base = (size_t)bid * 8 * 4096 + tid * 16;
  float hrun[16];
#pragma unroll
  for (int e = 0; e < 16; ++e) hrun[e] = 0.f;
  for (int c = 0; c < 8; ++c) {
    const size_t p = base + (size_t)c * 4096;
    u16x8 v0 = *(const u16x8*)&hst[p];
    u16x8 v1 = *(const u16x8*)&hst[p + 8];
    float ab = abprod[bh * 8 + c];
    u16x8 w0, w1;
#pragma unroll
    for (int e = 0; e < 8; ++e) { w0[e] = f2bf(hrun[e]); w1[e] = f2bf(hrun[8 + e]); }
    *(u16x8*)&hst[p] = w0;
    *(u16x8*)&hst[p + 8] = w1;
#pragma unroll
    for (int e = 0; e < 8; ++e) {
      hrun[e] = ab * hrun[e] + bf2f(v0[e]);
      hrun[8 + e] = ab * hrun[8 + e] + bf2f(v1[e]);
    }
  }
}

// ---------------- correction: yssm += pd[t] * (C_t . H_init) ------------------
// grid 1024 = b(2) x h(64) x ck(8); 256 threads = 4 waves. Wave w owns rows
// w*64..w*64+63 of the 256-row chunk. corr = C[256x128] * Hinit^T[128x64] via
// MFMA with fragments loaded directly from global (A: conv C-cols; B: hst).
__global__ __launch_bounds__(256) void correct_kernel(const ushort_t* __restrict__ conv,
                                                      const float* __restrict__ dtA,
                                                      const float* __restrict__ Avec,
                                                      const ushort_t* __restrict__ hst,
                                                      ushort_t* __restrict__ yssm) {
  const int bid = blockIdx.x;
  const int ck = bid & 7;
  const int h = (bid >> 3) & 63;
  const int b = bid >> 9;
  const int g = h >> 3;
  const int tid = threadIdx.x;
  const int lane = tid & 63;
  const int w = tid >> 6;
  const int lr = lane & 15, lk = lane >> 4;
  const int btb = (b << 11) + (ck << 8);

  // --- pd[t] = exp(A_h * inclusive_cumsum(dt)) over the 256-step chunk ---
  __shared__ float pdl[256];
  __shared__ float wsum[4];
  float s = dtA[(h << 13) + btb + tid];
#pragma unroll
  for (int off = 1; off < 64; off <<= 1) {
    float t = __shfl_up(s, off, 64);
    if (lane >= off) s += t;
  }
  if (lane == 63) wsum[w] = s;
  __syncthreads();
  float basev = 0.f;
  for (int i = 0; i < w; ++i) basev += wsum[i];
  pdl[tid] = expf(Avec[h] * (basev + s));
  __syncthreads();

  // --- MFMA: rows t = w*64 + mf*16 + lr; cols p = nf*16 + lr; K = 128 ---
  const ushort_t* Cc = conv + (size_t)btb * 6144 + 5120 + (g << 7);
  const size_t hb0 = ((size_t)((b << 10) | (h << 4) | (0 << 3) | ck)) * 4096;
  const size_t hb1 = ((size_t)((b << 10) | (h << 4) | (1 << 3) | ck)) * 4096;

  f32x4 acc[4][4] = {};
#pragma unroll
  for (int kk = 0; kk < 4; ++kk) {
    const int k0 = kk * 32 + lk * 8;
    bf16x8 afr[4], bfr[4];
#pragma unroll
    for (int mf = 0; mf < 4; ++mf) {
      const int t = w * 64 + mf * 16 + lr;
      afr[mf] = *(const bf16x8*)(Cc + (size_t)t * 6144 + k0);
    }
#pragma unroll
    for (int nf = 0; nf < 4; ++nf) {
      const int p = nf * 16 + lr;
      const size_t hb = (p < 32) ? hb0 : hb1;
      bfr[nf] = *(const bf16x8*)(hst + hb + (size_t)(p & 31) * 128 + k0);
    }
#pragma unroll
    for (int mf = 0; mf < 4; ++mf)
#pragma unroll
      for (int nf = 0; nf < 4; ++nf)
        acc[mf][nf] = __builtin_amdgcn_mfma_f32_16x16x32_bf16(afr[mf], bfr[nf],
                                                              acc[mf][nf], 0, 0, 0);
  }

  // --- epilogue: yssm[btb+row][h*64+p] += pd[row] * corr ---
#pragma unroll
  for (int mf = 0; mf < 4; ++mf) {
#pragma unroll
    for (int r = 0; r < 4; ++r) {
      const int row = w * 64 + mf * 16 + (lk << 2) + r;
      const float pd = pdl[row];
      const size_t yrow = (size_t)(btb + row) * 4096 + (h << 6);
#pragma unroll
      for (int nf = 0; nf < 4; ++nf) {
        const int p = nf * 16 + lr;
        const size_t idx = yrow + p;
        yssm[idx] = f2bf(bf2f(yssm[idx]) + pd * acc[mf][nf][r]);
      }
    }
  }
}

// ---------------- gate * silu + RMSNorm -> bf16 -------------------------------
__global__ __launch_bounds__(256) void norm_kernel(const ushort_t* __restrict__ yssm,
                                                   const ushort_t* __restrict__ gate,
                                                   const float* __restrict__ nw,
                                                   ushort_t* __restrict__ out) {
  const int bt = blockIdx.x;
  const int tid = threadIdx.x;
  const ushort_t* y = yssm + (size_t)bt * 4096;
  const ushort_t* gt = gate + (size_t)bt * 4096;
  float vals[16];
  float ss = 0.f;
#pragma unroll
  for (int j = 0; j < 4; ++j) {
    int o = (tid + j * 256) << 2;
    u16x4 yv = *(const u16x4*)(y + o);
    u16x4 gv = *(const u16x4*)(gt + o);
#pragma unroll
    for (int e = 0; e < 4; ++e) {
      float v = bf2f(yv[e]) * siluf(bf2f(gv[e]));
      vals[j * 4 + e] = v;
      ss += v * v;
    }
  }
#pragma unroll
  for (int m = 1; m <= 32; m <<= 1) ss += __shfl_xor(ss, m, 64);
  __shared__ float red[4];
  if ((tid & 63) == 0) red[tid >> 6] = ss;
  __syncthreads();
  ss = red[0] + red[1] + red[2] + red[3];
  const float sc = rsqrtf(ss * (1.f / 4096.f) + 1e-5f);
#pragma unroll
  for (int j = 0; j < 4; ++j) {
    int o = (tid + j * 256) << 2;
    f32x4 wv = *(const f32x4*)(nw + o);
    u16x4 ov;
    ov.x = f2bf(vals[j * 4 + 0] * sc * wv.x);
    ov.y = f2bf(vals[j * 4 + 1] * sc * wv.y);
    ov.z = f2bf(vals[j * 4 + 2] * sc * wv.z);
    ov.w = f2bf(vals[j * 4 + 3] * sc * wv.w);
    *(u16x4*)(out + (size_t)bt * 4096 + o) = ov;
  }
}

// ------------------------------------------------------------------------------
extern "C" void kernel_launch(void* const* d_in, const int* in_sizes, int n_in,
                              void* d_out, int out_size, void* d_ws, size_t ws_size,
                              hipStream_t stream) {
  const float* hidden  = (const float*)d_in[0];
  const float* w_in    = (const float*)d_in[1];
  const float* conv_w  = (const float*)d_in[2];
  const float* conv_b  = (const float*)d_in[3];
  const float* Avec    = (const float*)d_in[4];
  const float* Dvec    = (const float*)d_in[5];
  const float* dt_bias = (const float*)d_in[6];
  const float* nw      = (const float*)d_in[7];
  const float* w_out   = (const float*)d_in[8];
  float* out = (float*)d_out;

  char* ws = (char*)d_ws;
  // Region map (total 162,693,120 B) — unchanged from R4/R6.
  ushort_t* Xbf   = (ushort_t*)(ws);
  ushort_t* W1bf  = (ushort_t*)(ws + 22020096);
  ushort_t* gate  = (ushort_t*)(ws + 77758464);
  ushort_t* xbc   = (ushort_t*)(ws + 111312896);
  ushort_t* W2bf  = Xbf;
  ushort_t* convb = W1bf;
  float*    dtA   = (float*)(ws + 22020096 + 50331648);
  float*    abprod= (float*)(ws + 22020096 + 52428800);
  ushort_t* yssm  = xbc;
  ushort_t* hst   = (ushort_t*)(ws + 111312896 + 33554432);
  ushort_t* ynorm = convb;
  const size_t NEED = 162693120;
  if (NEED > ws_size) {
    fill_kernel<<<4, 256, 0, stream>>>(out, 12345.0f, 1024);   // sentinel: ws too small
    return;
  }

  cvt_bf16_kernel<<<10752, 256, 0, stream>>>(hidden, Xbf, 2752512, 2752512);
  cvt_bf16_kernel<<<27216, 256, 0, stream>>>(w_in, W1bf, 6924288, 6967296);
  gemm8_kernel<0><<<dim3(16, 41), 512, 0, stream>>>(Xbf, W1bf, gate, xbc,
                                                    2688, 10368, 10304, 21);
  cvt_bf16_kernel<<<10752, 256, 0, stream>>>(w_out, W2bf, 2752512, 2752512);
  conv_silu_kernel<<<24576, 256, 0, stream>>>(xbc, conv_w, conv_b, convb);
  dt_kernel<<<1024, 256, 0, stream>>>(xbc, dt_bias, Avec, dtA);
  scan_pass1_kernel<<<2048, 256, 0, stream>>>(convb, dtA, Dvec, Avec, yssm, hst, abprod);
  combine_kernel<<<256, 256, 0, stream>>>(hst, abprod);
  correct_kernel<<<1024, 256, 0, stream>>>(convb, dtA, Avec, hst, yssm);
  norm_kernel<<<4096, 256, 0, stream>>>(yssm, gate, nw, ynorm);
  gemm8_kernel<1><<<dim3(16, 11), 512, 0, stream>>>(ynorm, W2bf, out, nullptr,
                                                    4096, 2688, 2688, 32);
}

// Round 8
// 727.805 us; speedup vs baseline: 1.4467x; 1.0854x over previous
//
#include <hip/hip_runtime.h>
#include <stdint.h>

typedef unsigned short ushort_t;
typedef __attribute__((ext_vector_type(4))) float f32x4;
typedef __attribute__((ext_vector_type(2))) float f32x2;
typedef __attribute__((ext_vector_type(8))) __bf16 bf16x8;
typedef __attribute__((ext_vector_type(4))) unsigned short u16x4;
typedef __attribute__((ext_vector_type(8))) unsigned short u16x8;

#define DEV __device__ __forceinline__

// async global->LDS, 16B per lane. HW: dest = wave-uniform base + laneID*16.
DEV void gload_lds16(const void* g, void* l) {
  __builtin_amdgcn_global_load_lds(
      (const __attribute__((address_space(1))) uint32_t*)(uintptr_t)(g),
      (__attribute__((address_space(3))) uint32_t*)(uintptr_t)(l), 16, 0, 0);
}

DEV ushort_t f2bf(float f) {
  union { float f; uint32_t u; } x; x.f = f;
  x.u += 0x7fffu + ((x.u >> 16) & 1u);   // RNE
  return (ushort_t)(x.u >> 16);
}

DEV float bf2f(ushort_t u) {
  union { uint32_t u; float f; } x; x.u = (uint32_t)u << 16; return x.f;
}

DEV float siluf(float x) { return x / (1.f + expf(-x)); }

#define BAR asm volatile("s_barrier" ::: "memory")
#define LGKM0 do { asm volatile("s_waitcnt lgkmcnt(0)" ::: "memory"); \
                   __builtin_amdgcn_sched_barrier(0); } while (0)
#define VMCNT(n) asm volatile("s_waitcnt vmcnt(" #n ")" ::: "memory")

// ---------------- sentinel fill (diagnostic) ----------------------------------
__global__ __launch_bounds__(256) void fill_kernel(float* p, float v, int n) {
  int i = blockIdx.x * 256 + threadIdx.x;
  if (i < n) p[i] = v;
}

// ---------------- f32 -> bf16 convert (with zero tail padding) ---------------
__global__ __launch_bounds__(256) void cvt_bf16_kernel(const float* __restrict__ src,
                                                       ushort_t* __restrict__ dst,
                                                       int n_src4, int n_dst4) {
  int i = blockIdx.x * 256 + threadIdx.x;
  if (i >= n_dst4) return;
  f32x4 v;
  if (i < n_src4) v = *(const f32x4*)(src + (size_t)i * 4);
  else { v.x = 0.f; v.y = 0.f; v.z = 0.f; v.w = 0.f; }
  u16x4 o;
  o.x = f2bf(v.x); o.y = f2bf(v.y); o.z = f2bf(v.z); o.w = f2bf(v.w);
  *(u16x4*)(dst + (size_t)i * 4) = o;
}

// ================= 256x256 8-phase bf16 GEMM (T2+T3+T4+T5) ====================
// (unchanged from R6/R7 PASS — see R5/R6 notes for vmcnt discipline)
DEV void ld_a4(const unsigned char* ab2, int mgofs, int ck0, int ck1, bf16x8 (&af)[4][2]) {
#pragma unroll
  for (int mi = 0; mi < 4; ++mi) {
    const unsigned char* p = ab2 + (mgofs + mi * 16) * 128;
    af[mi][0] = *(const bf16x8*)(p + ck0);
    af[mi][1] = *(const bf16x8*)(p + ck1);
  }
}

DEV void ld_b2(const unsigned char* bb2, int npofs, int ck0, int ck1, bf16x8 (&bf)[2][2]) {
#pragma unroll
  for (int ni = 0; ni < 2; ++ni) {
    const unsigned char* p = bb2 + (npofs + ni * 16) * 128;
    bf[ni][0] = *(const bf16x8*)(p + ck0);
    bf[ni][1] = *(const bf16x8*)(p + ck1);
  }
}

DEV void mm16(f32x4 (&acc)[8][4], const bf16x8 (&af)[4][2], const bf16x8 (&bf)[2][2],
              int mb, int nb) {
  __builtin_amdgcn_s_setprio(1);
#pragma unroll
  for (int mi = 0; mi < 4; ++mi)
#pragma unroll
    for (int ni = 0; ni < 2; ++ni)
#pragma unroll
      for (int kk = 0; kk < 2; ++kk)
        acc[mb + mi][nb + ni] = __builtin_amdgcn_mfma_f32_16x16x32_bf16(
            af[mi][kk], bf[ni][kk], acc[mb + mi][nb + ni], 0, 0, 0);
  __builtin_amdgcn_s_setprio(0);
}

DEV void stage2(const ushort_t* s0, const ushort_t* s1, unsigned char* d) {
  gload_lds16(s0, d);
  gload_lds16(s1, d + 8192);
}

template <int MODE>
__global__ __launch_bounds__(512, 1) void gemm8_kernel(const ushort_t* __restrict__ A,
                                                       const ushort_t* __restrict__ B,
                                                       void* __restrict__ C0,
                                                       void* __restrict__ C1,
                                                       int K, int NB, int NC, int niter) {
  __shared__ __align__(16) unsigned char lds[131072];
  const int tid = threadIdx.x;
  const int l = tid & 63, w = tid >> 6;
  const int wr = w >> 2, wc = w & 3;
  const int lr = l & 15, lk = l >> 4;
  const int xm = (lr & 7) << 4;
  const int ck0 = (lk * 16) ^ xm;
  const int ck1 = (64 + lk * 16) ^ xm;
  const int bm = blockIdx.x, bn = blockIdx.y;

  const int rr = (w << 3) + (l >> 3);
  const int cE = ((l & 7) ^ (l >> 3)) << 3;
  const int dstoff = w * 1024 + l * 16;

  const ushort_t* sA00 = A + (size_t)(bm * 256 +       rr) * K + cE;
  const ushort_t* sA01 = A + (size_t)(bm * 256 +  64 + rr) * K + cE;
  const ushort_t* sA10 = A + (size_t)(bm * 256 + 128 + rr) * K + cE;
  const ushort_t* sA11 = A + (size_t)(bm * 256 + 192 + rr) * K + cE;
  int rb0 = bn * 256 +       rr; if (rb0 > NB - 1) rb0 = NB - 1;
  int rb1 = bn * 256 +  64 + rr; if (rb1 > NB - 1) rb1 = NB - 1;
  int rb2 = bn * 256 + 128 + rr; if (rb2 > NB - 1) rb2 = NB - 1;
  int rb3 = bn * 256 + 192 + rr; if (rb3 > NB - 1) rb3 = NB - 1;
  const ushort_t* sB00 = B + (size_t)rb0 * K + cE;
  const ushort_t* sB01 = B + (size_t)rb1 * K + cE;
  const ushort_t* sB10 = B + (size_t)rb2 * K + cE;
  const ushort_t* sB11 = B + (size_t)rb3 * K + cE;

  const int aoff = wr * 16384 + lr * 128;
  const int boff = 32768 + (wc >> 1) * 16384 + ((wc & 1) * 64 + lr) * 128;

  f32x4 acc[8][4] = {};
  bf16x8 af[4][2], bf[2][2], bg[2][2];

  stage2(sA00, sA01, lds + dstoff);
  stage2(sA10, sA11, lds + 16384 + dstoff);
  stage2(sB00, sB01, lds + 32768 + dstoff);
  stage2(sB10, sB11, lds + 49152 + dstoff);
  stage2(sA00 + 64, sA01 + 64, lds + 65536 + dstoff);
  VMCNT(2);
  BAR;

  auto kpair = [&](int kt0, bool last) {
    const unsigned char* a0 = lds + aoff;
    const unsigned char* b0 = lds + boff;
    const unsigned char* a1 = lds + 65536 + aoff;
    const unsigned char* b1 = lds + 65536 + boff;
    const size_t c1 = (size_t)(kt0 + 1) * 64;
    const size_t c2 = (size_t)(kt0 + 2) * 64;
    const size_t c3 = (size_t)(kt0 + 3) * 64;
    ld_a4(a0, 0, ck0, ck1, af);
    ld_b2(b0, 0, ck0, ck1, bf);
    stage2(sA10 + c1, sA11 + c1, lds + 65536 + 16384 + dstoff);
    BAR; LGKM0; mm16(acc, af, bf, 0, 0); BAR;
    ld_b2(b0, 32, ck0, ck1, bg);
    stage2(sB00 + c1, sB01 + c1, lds + 65536 + 32768 + dstoff);
    BAR; LGKM0; mm16(acc, af, bg, 0, 2); BAR;
    ld_a4(a0, 64, ck0, ck1, af);
    stage2(sB10 + c1, sB11 + c1, lds + 65536 + 49152 + dstoff);
    BAR; LGKM0; mm16(acc, af, bg, 4, 2); BAR;
    ld_b2(b0, 0, ck0, ck1, bf);
    if (!last) { stage2(sA00 + c2, sA01 + c2, lds + dstoff); VMCNT(2); }
    else       { VMCNT(0); }
    BAR; LGKM0; mm16(acc, af, bf, 4, 0); BAR;
    ld_a4(a1, 0, ck0, ck1, af);
    ld_b2(b1, 0, ck0, ck1, bf);
    if (!last) stage2(sA10 + c2, sA11 + c2, lds + 16384 + dstoff);
    BAR; LGKM0; mm16(acc, af, bf, 0, 0); BAR;
    ld_b2(b1, 32, ck0, ck1, bg);
    if (!last) stage2(sB00 + c2, sB01 + c2, lds + 32768 + dstoff);
    BAR; LGKM0; mm16(acc, af, bg, 0, 2); BAR;
    ld_a4(a1, 64, ck0, ck1, af);
    if (!last) stage2(sB10 + c2, sB11 + c2, lds + 49152 + dstoff);
    BAR; LGKM0; mm16(acc, af, bg, 4, 2); BAR;
    ld_b2(b1, 0, ck0, ck1, bf);
    if (!last) { stage2(sA00 + c3, sA01 + c3, lds + 65536 + dstoff); VMCNT(2); }
    BAR; LGKM0; mm16(acc, af, bf, 4, 0); BAR;
  };

  for (int it = 0; it < niter - 1; ++it) kpair(2 * it, false);
  kpair(2 * (niter - 1), true);

  const int crow0 = bm * 256 + wr * 128 + (lk << 2);
  const int ccol0 = bn * 256 + wc * 64 + lr;
  if (MODE == 0) {
    ushort_t* gate = (ushort_t*)C0;
    ushort_t* xbc  = (ushort_t*)C1;
#pragma unroll
    for (int ni = 0; ni < 4; ++ni) {
      const int col = ccol0 + ni * 16;
      if (col < NC) {
        ushort_t* dst; size_t stride;
        if (col < 4096) { dst = gate + col; stride = 4096; }
        else            { dst = xbc + (col - 4096); stride = 6272; }
#pragma unroll
        for (int mi = 0; mi < 8; ++mi)
#pragma unroll
          for (int r = 0; r < 4; ++r)
            dst[(size_t)(crow0 + mi * 16 + r) * stride] = f2bf(acc[mi][ni][r]);
      }
    }
  } else {
    float* o = (float*)C0;
#pragma unroll
    for (int ni = 0; ni < 4; ++ni) {
      const int col = ccol0 + ni * 16;
      if (col < NC) {
#pragma unroll
        for (int mi = 0; mi < 8; ++mi)
#pragma unroll
          for (int r = 0; r < 4; ++r)
            o[(size_t)(crow0 + mi * 16 + r) * NC + col] = acc[mi][ni][r];
      }
    }
  }
}

// ---------------- causal depthwise conv (K=4) + bias + SiLU, bf16 in/out ------
__global__ __launch_bounds__(256) void conv_silu_kernel(const ushort_t* __restrict__ xbc,
                                                        const float* __restrict__ cw,
                                                        const float* __restrict__ cb,
                                                        ushort_t* __restrict__ out) {
  int idx = blockIdx.x * 256 + threadIdx.x;      // 4096*1536
  int c4 = (idx % 1536) << 2;
  int bt = idx / 1536;
  int t = bt & 2047;
  const ushort_t* base = xbc + (size_t)bt * 6272 + c4;
  f32x4 w0 = *(const f32x4*)&cw[(c4 + 0) * 4];
  f32x4 w1 = *(const f32x4*)&cw[(c4 + 1) * 4];
  f32x4 w2 = *(const f32x4*)&cw[(c4 + 2) * 4];
  f32x4 w3 = *(const f32x4*)&cw[(c4 + 3) * 4];
  f32x4 acc = *(const f32x4*)&cb[c4];
#pragma unroll
  for (int i = 0; i < 4; ++i) {
    int dt_ = i - 3;
    if (t + dt_ >= 0) {
      u16x4 xv = *(const u16x4*)(base + (ptrdiff_t)dt_ * 6272);
      acc.x += bf2f(xv.x) * w0[i];
      acc.y += bf2f(xv.y) * w1[i];
      acc.z += bf2f(xv.z) * w2[i];
      acc.w += bf2f(xv.w) * w3[i];
    }
  }
  u16x4 o;
  o.x = f2bf(siluf(acc.x)); o.y = f2bf(siluf(acc.y));
  o.z = f2bf(siluf(acc.z)); o.w = f2bf(siluf(acc.w));
  *(u16x4*)(out + (size_t)bt * 6144 + c4) = o;
}

// ---------------- dt: softplus + exp(A*dt), layout [H][2][BT] f32 -------------
__global__ __launch_bounds__(256) void dt_kernel(const ushort_t* __restrict__ xbc,
                                                 const float* __restrict__ dt_bias,
                                                 const float* __restrict__ Avec,
                                                 float* __restrict__ dtA) {
  int idx = blockIdx.x * 256 + threadIdx.x;      // 64*4096
  int h = idx >> 12, bt = idx & 4095;
  float v = bf2f(xbc[(size_t)bt * 6272 + 6144 + h]) + dt_bias[h];
  float sp = fmaxf(v, 0.f) + log1pf(expf(-fabsf(v)));
  float ab = expf(Avec[h] * sp);
  dtA[(h << 13) + bt] = sp;
  dtA[(h << 13) + 4096 + bt] = ab;
}

// ---------------- scan pass 1: zero-init, emit y, write final state ----------
// grid 1024 = B(2) x H(64) x Chunk(8); thread = 4p x 8n = 32 states (f32x2
// packed pairs -> v_pk_fma_f32). y here EXCLUDES inter-chunk contribution;
// correct_kernel adds pd[t] * (C_t . H_init) afterwards.
// hst/abprod layouts identical to R7 (combine/correct unchanged).
__global__ __launch_bounds__(256) void scan_pass1_kernel(const ushort_t* __restrict__ conv,
                                                         const float* __restrict__ dtA,
                                                         const float* __restrict__ Dvec,
                                                         const float* __restrict__ Avec,
                                                         ushort_t* __restrict__ yssm,
                                                         ushort_t* __restrict__ hst,
                                                         float* __restrict__ abprod) {
  const int bid = blockIdx.x;
  const int ck = bid & 7;
  const int h = (bid >> 3) & 63;
  const int b = bid >> 9;
  const int g = h >> 3;
  const int tid = threadIdx.x;
  const int lane = tid & 63;
  const int wave = tid >> 6;
  const int pg = tid & 15, ng = tid >> 4;
  const int p0 = pg << 2, n0 = (ng & 15) << 3;

  // per buf: x bf16[8][64] @0 (1024B), B bf16[8][128] @1024, C @3072,
  //          dt f32[8] @5120, ab f32[8] @5152  -> 5184 B (324 x 16B chunks)
  __shared__ __align__(16) unsigned char sraw[2][5184];
  __shared__ __align__(16) float ypart[2][4][8][64];

  const int btbase = (b << 11) + (ck << 8);
  const float* dt0 = dtA + (h << 13) + btbase;
  const float* dt1 = dt0 + 4096;
  const float Dh = Dvec[h];
  const int xcol = h << 6;

  auto stage = [&](int tb) {
    unsigned char* dst = sraw[tb & 1];
    const int t0 = tb << 3;
    const size_t row0 = (size_t)(btbase + t0) * 6144;
#pragma unroll
    for (int j = 0; j < 2; ++j) {
      int c = tid + (j << 8);
      if (c < 324) {
        const void* src;
        if (c < 64)       { src = conv + row0 + (size_t)(c >> 3) * 6144 + xcol + ((c & 7) << 3); }
        else if (c < 192) { int r = c - 64;  src = conv + row0 + (size_t)(r >> 4) * 6144 + 4096 + (g << 7) + ((r & 15) << 3); }
        else if (c < 320) { int r = c - 192; src = conv + row0 + (size_t)(r >> 4) * 6144 + 5120 + (g << 7) + ((r & 15) << 3); }
        else if (c < 322) { src = dt0 + t0 + ((c - 320) << 2); }
        else              { src = dt1 + t0 + ((c - 322) << 2); }
        gload_lds16(src, dst + ((size_t)c << 4));
      }
    }
  };

  stage(0);

  f32x2 hsA[8], hsB[8];           // p0,p0+1 and p0+2,p0+3
#pragma unroll
  for (int n = 0; n < 8; ++n) { hsA[n] = (f32x2)(0.f); hsB[n] = (f32x2)(0.f); }
  float dtsum = 0.f;

  for (int tb = 0; tb < 32; ++tb) {
    __syncthreads();
    if (tb > 0) {
      const int cur = (tb - 1) & 1;
      const int tprev = btbase + ((tb - 1) << 3);
#pragma unroll
      for (int r2 = 0; r2 < 2; ++r2) {
        int idx = tid + (r2 << 8);
        int tt = idx >> 6, p = idx & 63;
        float v = ypart[cur][0][tt][p] + ypart[cur][1][tt][p] +
                  ypart[cur][2][tt][p] + ypart[cur][3][tt][p];
        yssm[(size_t)(tprev + tt) * 4096 + xcol + p] = f2bf(v);
      }
    }
    if (tb + 1 < 32) stage(tb + 1);
    const ushort_t* sbu = (const ushort_t*)sraw[tb & 1];
    const float* sfs = (const float*)(sraw[tb & 1] + 5120);
    const int cur = tb & 1;
#pragma unroll
    for (int tt = 0; tt < 8; ++tt) {
      u16x4 xv = *(const u16x4*)&sbu[(tt << 6) + p0];
      f32x2 xa, xb;
      xa.x = bf2f(xv.x); xa.y = bf2f(xv.y);
      xb.x = bf2f(xv.z); xb.y = bf2f(xv.w);
      u16x8 bv = *(const u16x8*)&sbu[512 + (tt << 7) + n0];
      u16x8 cv = *(const u16x8*)&sbu[1536 + (tt << 7) + n0];
      const float dtv = sfs[tt], abv = sfs[8 + tt];
      dtsum += dtv;
      f32x2 ab2; ab2.x = abv; ab2.y = abv;
      f32x2 da = dtv * xa, db = dtv * xb;
      f32x2 ya = (f32x2)(0.f), yb = (f32x2)(0.f);
#pragma unroll
      for (int n = 0; n < 8; ++n) {
        const float Bn = bf2f(bv[n]);
        const float Cn = bf2f(cv[n]);
        f32x2 b2; b2.x = Bn; b2.y = Bn;
        f32x2 c2; c2.x = Cn; c2.y = Cn;
        hsA[n] = ab2 * hsA[n] + da * b2;  ya += hsA[n] * c2;
        hsB[n] = ab2 * hsB[n] + db * b2;  yb += hsB[n] * c2;
      }
      float y0 = ya.x, y1 = ya.y, y2 = yb.x, y3 = yb.y;
      y0 += __shfl_xor(y0, 16, 64); y0 += __shfl_xor(y0, 32, 64);
      y1 += __shfl_xor(y1, 16, 64); y1 += __shfl_xor(y1, 32, 64);
      y2 += __shfl_xor(y2, 16, 64); y2 += __shfl_xor(y2, 32, 64);
      y3 += __shfl_xor(y3, 16, 64); y3 += __shfl_xor(y3, 32, 64);
      if (wave == 0) {
        y0 += Dh * xa.x; y1 += Dh * xa.y;
        y2 += Dh * xb.x; y3 += Dh * xb.y;
      }
      if ((lane >> 4) == 0) {
        f32x4 o; o.x = y0; o.y = y1; o.z = y2; o.w = y3;
        *(f32x4*)&ypart[cur][wave][tt][p0] = o;
      }
    }
  }
  // final chunk state (zero-init scan) + abprod — layout identical to R7:
  // hst[((b<<10)|(h<<4)|(ph<<3)|ck)*4096 + (p&31)*128 + n]
  {
#pragma unroll
    for (int i = 0; i < 4; ++i) {
      const int p = p0 + i;
      const size_t hb = ((size_t)((b << 10) | (h << 4) | ((p >> 5) << 3) | ck)) * 4096;
      u16x8 o;
      if (i < 2) {
#pragma unroll
        for (int n = 0; n < 8; ++n) o[n] = f2bf((i == 0) ? hsA[n].x : hsA[n].y);
      } else {
#pragma unroll
        for (int n = 0; n < 8; ++n) o[n] = f2bf((i == 2) ? hsB[n].x : hsB[n].y);
      }
      *(u16x8*)&hst[hb + (size_t)(p & 31) * 128 + n0] = o;
    }
    if (tid == 0)
      abprod[((b << 6) + h) * 8 + ck] = expf(Avec[h] * dtsum);
  }
  __syncthreads();
  {
    const int cur = 31 & 1;
    const int tprev = btbase + (31 << 3);
#pragma unroll
    for (int r2 = 0; r2 < 2; ++r2) {
      int idx = tid + (r2 << 8);
      int tt = idx >> 6, p = idx & 63;
      float v = ypart[cur][0][tt][p] + ypart[cur][1][tt][p] +
                ypart[cur][2][tt][p] + ypart[cur][3][tt][p];
      yssm[(size_t)(tprev + tt) * 4096 + xcol + p] = f2bf(v);
    }
  }
}

// ---------------- combine: prefix over chunk states (in place) ----------------
__global__ __launch_bounds__(256) void combine_kernel(ushort_t* __restrict__ hst,
                                                      const float* __restrict__ abprod) {
  const int bid = blockIdx.x;
  const int bh = bid >> 1;
  const int tid = threadIdx.x;
  const size_t base = (size_t)bid * 8 * 4096 + tid * 16;
  float hrun[16];
#pragma unroll
  for (int e = 0; e < 16; ++e) hrun[e] = 0.f;
  for (int c = 0; c < 8; ++c) {
    const size_t p = base + (size_t)c * 4096;
    u16x8 v0 = *(const u16x8*)&hst[p];
    u16x8 v1 = *(const u16x8*)&hst[p + 8];
    float ab = abprod[bh * 8 + c];
    u16x8 w0, w1;
#pragma unroll
    for (int e = 0; e < 8; ++e) { w0[e] = f2bf(hrun[e]); w1[e] = f2bf(hrun[8 + e]); }
    *(u16x8*)&hst[p] = w0;
    *(u16x8*)&hst[p + 8] = w1;
#pragma unroll
    for (int e = 0; e < 8; ++e) {
      hrun[e] = ab * hrun[e] + bf2f(v0[e]);
      hrun[8 + e] = ab * hrun[8 + e] + bf2f(v1[e]);
    }
  }
}

// ---------------- correction: yssm += pd[t] * (C_t . H_init) ------------------
__global__ __launch_bounds__(256) void correct_kernel(const ushort_t* __restrict__ conv,
                                                      const float* __restrict__ dtA,
                                                      const float* __restrict__ Avec,
                                                      const ushort_t* __restrict__ hst,
                                                      ushort_t* __restrict__ yssm) {
  const int bid = blockIdx.x;
  const int ck = bid & 7;
  const int h = (bid >> 3) & 63;
  const int b = bid >> 9;
  const int g = h >> 3;
  const int tid = threadIdx.x;
  const int lane = tid & 63;
  const int w = tid >> 6;
  const int lr = lane & 15, lk = lane >> 4;
  const int btb = (b << 11) + (ck << 8);

  __shared__ float pdl[256];
  __shared__ float wsum[4];
  float s = dtA[(h << 13) + btb + tid];
#pragma unroll
  for (int off = 1; off < 64; off <<= 1) {
    float t = __shfl_up(s, off, 64);
    if (lane >= off) s += t;
  }
  if (lane == 63) wsum[w] = s;
  __syncthreads();
  float basev = 0.f;
  for (int i = 0; i < w; ++i) basev += wsum[i];
  pdl[tid] = expf(Avec[h] * (basev + s));
  __syncthreads();

  const ushort_t* Cc = conv + (size_t)btb * 6144 + 5120 + (g << 7);
  const size_t hb0 = ((size_t)((b << 10) | (h << 4) | (0 << 3) | ck)) * 4096;
  const size_t hb1 = ((size_t)((b << 10) | (h << 4) | (1 << 3) | ck)) * 4096;

  f32x4 acc[4][4] = {};
#pragma unroll
  for (int kk = 0; kk < 4; ++kk) {
    const int k0 = kk * 32 + lk * 8;
    bf16x8 afr[4], bfr[4];
#pragma unroll
    for (int mf = 0; mf < 4; ++mf) {
      const int t = w * 64 + mf * 16 + lr;
      afr[mf] = *(const bf16x8*)(Cc + (size_t)t * 6144 + k0);
    }
#pragma unroll
    for (int nf = 0; nf < 4; ++nf) {
      const int p = nf * 16 + lr;
      const size_t hb = (p < 32) ? hb0 : hb1;
      bfr[nf] = *(const bf16x8*)(hst + hb + (size_t)(p & 31) * 128 + k0);
    }
#pragma unroll
    for (int mf = 0; mf < 4; ++mf)
#pragma unroll
      for (int nf = 0; nf < 4; ++nf)
        acc[mf][nf] = __builtin_amdgcn_mfma_f32_16x16x32_bf16(afr[mf], bfr[nf],
                                                              acc[mf][nf], 0, 0, 0);
  }

#pragma unroll
  for (int mf = 0; mf < 4; ++mf) {
#pragma unroll
    for (int r = 0; r < 4; ++r) {
      const int row = w * 64 + mf * 16 + (lk << 2) + r;
      const float pd = pdl[row];
      const size_t yrow = (size_t)(btb + row) * 4096 + (h << 6);
#pragma unroll
      for (int nf = 0; nf < 4; ++nf) {
        const int p = nf * 16 + lr;
        const size_t idx = yrow + p;
        yssm[idx] = f2bf(bf2f(yssm[idx]) + pd * acc[mf][nf][r]);
      }
    }
  }
}

// ---------------- gate * silu + RMSNorm -> bf16 -------------------------------
__global__ __launch_bounds__(256) void norm_kernel(const ushort_t* __restrict__ yssm,
                                                   const ushort_t* __restrict__ gate,
                                                   const float* __restrict__ nw,
                                                   ushort_t* __restrict__ out) {
  const int bt = blockIdx.x;
  const int tid = threadIdx.x;
  const ushort_t* y = yssm + (size_t)bt * 4096;
  const ushort_t* gt = gate + (size_t)bt * 4096;
  float vals[16];
  float ss = 0.f;
#pragma unroll
  for (int j = 0; j < 4; ++j) {
    int o = (tid + j * 256) << 2;
    u16x4 yv = *(const u16x4*)(y + o);
    u16x4 gv = *(const u16x4*)(gt + o);
#pragma unroll
    for (int e = 0; e < 4; ++e) {
      float v = bf2f(yv[e]) * siluf(bf2f(gv[e]));
      vals[j * 4 + e] = v;
      ss += v * v;
    }
  }
#pragma unroll
  for (int m = 1; m <= 32; m <<= 1) ss += __shfl_xor(ss, m, 64);
  __shared__ float red[4];
  if ((tid & 63) == 0) red[tid >> 6] = ss;
  __syncthreads();
  ss = red[0] + red[1] + red[2] + red[3];
  const float sc = rsqrtf(ss * (1.f / 4096.f) + 1e-5f);
#pragma unroll
  for (int j = 0; j < 4; ++j) {
    int o = (tid + j * 256) << 2;
    f32x4 wv = *(const f32x4*)(nw + o);
    u16x4 ov;
    ov.x = f2bf(vals[j * 4 + 0] * sc * wv.x);
    ov.y = f2bf(vals[j * 4 + 1] * sc * wv.y);
    ov.z = f2bf(vals[j * 4 + 2] * sc * wv.z);
    ov.w = f2bf(vals[j * 4 + 3] * sc * wv.w);
    *(u16x4*)(out + (size_t)bt * 4096 + o) = ov;
  }
}

// ------------------------------------------------------------------------------
extern "C" void kernel_launch(void* const* d_in, const int* in_sizes, int n_in,
                              void* d_out, int out_size, void* d_ws, size_t ws_size,
                              hipStream_t stream) {
  const float* hidden  = (const float*)d_in[0];
  const float* w_in    = (const float*)d_in[1];
  const float* conv_w  = (const float*)d_in[2];
  const float* conv_b  = (const float*)d_in[3];
  const float* Avec    = (const float*)d_in[4];
  const float* Dvec    = (const float*)d_in[5];
  const float* dt_bias = (const float*)d_in[6];
  const float* nw      = (const float*)d_in[7];
  const float* w_out   = (const float*)d_in[8];
  float* out = (float*)d_out;

  char* ws = (char*)d_ws;
  // Region map (total 162,693,120 B) — unchanged from R4/R6/R7.
  ushort_t* Xbf   = (ushort_t*)(ws);
  ushort_t* W1bf  = (ushort_t*)(ws + 22020096);
  ushort_t* gate  = (ushort_t*)(ws + 77758464);
  ushort_t* xbc   = (ushort_t*)(ws + 111312896);
  ushort_t* W2bf  = Xbf;
  ushort_t* convb = W1bf;
  float*    dtA   = (float*)(ws + 22020096 + 50331648);
  float*    abprod= (float*)(ws + 22020096 + 52428800);
  ushort_t* yssm  = xbc;
  ushort_t* hst   = (ushort_t*)(ws + 111312896 + 33554432);
  ushort_t* ynorm = convb;
  const size_t NEED = 162693120;
  if (NEED > ws_size) {
    fill_kernel<<<4, 256, 0, stream>>>(out, 12345.0f, 1024);   // sentinel: ws too small
    return;
  }

  cvt_bf16_kernel<<<10752, 256, 0, stream>>>(hidden, Xbf, 2752512, 2752512);
  cvt_bf16_kernel<<<27216, 256, 0, stream>>>(w_in, W1bf, 6924288, 6967296);
  gemm8_kernel<0><<<dim3(16, 41), 512, 0, stream>>>(Xbf, W1bf, gate, xbc,
                                                    2688, 10368, 10304, 21);
  cvt_bf16_kernel<<<10752, 256, 0, stream>>>(w_out, W2bf, 2752512, 2752512);
  conv_silu_kernel<<<24576, 256, 0, stream>>>(xbc, conv_w, conv_b, convb);
  dt_kernel<<<1024, 256, 0, stream>>>(xbc, dt_bias, Avec, dtA);
  scan_pass1_kernel<<<1024, 256, 0, stream>>>(convb, dtA, Dvec, Avec, yssm, hst, abprod);
  combine_kernel<<<256, 256, 0, stream>>>(hst, abprod);
  correct_kernel<<<1024, 256, 0, stream>>>(convb, dtA, Avec, hst, yssm);
  norm_kernel<<<4096, 256, 0, stream>>>(yssm, gate, nw, ynorm);
  gemm8_kernel<1><<<dim3(16, 11), 512, 0, stream>>>(ynorm, W2bf, out, nullptr,
                                                    4096, 2688, 2688, 32);
}

// Round 9
// 709.489 us; speedup vs baseline: 1.4840x; 1.0258x over previous
//
#include <hip/hip_runtime.h>
#include <stdint.h>

typedef unsigned short ushort_t;
typedef __attribute__((ext_vector_type(4))) float f32x4;
typedef __attribute__((ext_vector_type(2))) float f32x2;
typedef __attribute__((ext_vector_type(8))) __bf16 bf16x8;
typedef __attribute__((ext_vector_type(4))) unsigned short u16x4;
typedef __attribute__((ext_vector_type(8))) unsigned short u16x8;

#define DEV __device__ __forceinline__

// async global->LDS, 16B per lane. HW: dest = wave-uniform base + laneID*16.
DEV void gload_lds16(const void* g, void* l) {
  __builtin_amdgcn_global_load_lds(
      (const __attribute__((address_space(1))) uint32_t*)(uintptr_t)(g),
      (__attribute__((address_space(3))) uint32_t*)(uintptr_t)(l), 16, 0, 0);
}

DEV ushort_t f2bf(float f) {
  union { float f; uint32_t u; } x; x.f = f;
  x.u += 0x7fffu + ((x.u >> 16) & 1u);   // RNE
  return (ushort_t)(x.u >> 16);
}

DEV float bf2f(ushort_t u) {
  union { uint32_t u; float f; } x; x.u = (uint32_t)u << 16; return x.f;
}

DEV float siluf(float x) { return x / (1.f + expf(-x)); }

#define BAR asm volatile("s_barrier" ::: "memory")
#define LGKM0 do { asm volatile("s_waitcnt lgkmcnt(0)" ::: "memory"); \
                   __builtin_amdgcn_sched_barrier(0); } while (0)
#define VMCNT(n) asm volatile("s_waitcnt vmcnt(" #n ")" ::: "memory")

// ---------------- sentinel fill (diagnostic) ----------------------------------
__global__ __launch_bounds__(256) void fill_kernel(float* p, float v, int n) {
  int i = blockIdx.x * 256 + threadIdx.x;
  if (i < n) p[i] = v;
}

// ---------------- f32 -> bf16 convert (with zero tail padding) ---------------
__global__ __launch_bounds__(256) void cvt_bf16_kernel(const float* __restrict__ src,
                                                       ushort_t* __restrict__ dst,
                                                       int n_src4, int n_dst4) {
  int i = blockIdx.x * 256 + threadIdx.x;
  if (i >= n_dst4) return;
  f32x4 v;
  if (i < n_src4) v = *(const f32x4*)(src + (size_t)i * 4);
  else { v.x = 0.f; v.y = 0.f; v.z = 0.f; v.w = 0.f; }
  u16x4 o;
  o.x = f2bf(v.x); o.y = f2bf(v.y); o.z = f2bf(v.z); o.w = f2bf(v.w);
  *(u16x4*)(dst + (size_t)i * 4) = o;
}

// ================= 256x256 8-phase bf16 GEMM (T2+T3+T4+T5) ====================
// (unchanged from R6/R7/R8 PASS — see R5/R6 notes for vmcnt discipline)
DEV void ld_a4(const unsigned char* ab2, int mgofs, int ck0, int ck1, bf16x8 (&af)[4][2]) {
#pragma unroll
  for (int mi = 0; mi < 4; ++mi) {
    const unsigned char* p = ab2 + (mgofs + mi * 16) * 128;
    af[mi][0] = *(const bf16x8*)(p + ck0);
    af[mi][1] = *(const bf16x8*)(p + ck1);
  }
}

DEV void ld_b2(const unsigned char* bb2, int npofs, int ck0, int ck1, bf16x8 (&bf)[2][2]) {
#pragma unroll
  for (int ni = 0; ni < 2; ++ni) {
    const unsigned char* p = bb2 + (npofs + ni * 16) * 128;
    bf[ni][0] = *(const bf16x8*)(p + ck0);
    bf[ni][1] = *(const bf16x8*)(p + ck1);
  }
}

DEV void mm16(f32x4 (&acc)[8][4], const bf16x8 (&af)[4][2], const bf16x8 (&bf)[2][2],
              int mb, int nb) {
  __builtin_amdgcn_s_setprio(1);
#pragma unroll
  for (int mi = 0; mi < 4; ++mi)
#pragma unroll
    for (int ni = 0; ni < 2; ++ni)
#pragma unroll
      for (int kk = 0; kk < 2; ++kk)
        acc[mb + mi][nb + ni] = __builtin_amdgcn_mfma_f32_16x16x32_bf16(
            af[mi][kk], bf[ni][kk], acc[mb + mi][nb + ni], 0, 0, 0);
  __builtin_amdgcn_s_setprio(0);
}

DEV void stage2(const ushort_t* s0, const ushort_t* s1, unsigned char* d) {
  gload_lds16(s0, d);
  gload_lds16(s1, d + 8192);
}

template <int MODE>
__global__ __launch_bounds__(512, 1) void gemm8_kernel(const ushort_t* __restrict__ A,
                                                       const ushort_t* __restrict__ B,
                                                       void* __restrict__ C0,
                                                       void* __restrict__ C1,
                                                       int K, int NB, int NC, int niter) {
  __shared__ __align__(16) unsigned char lds[131072];
  const int tid = threadIdx.x;
  const int l = tid & 63, w = tid >> 6;
  const int wr = w >> 2, wc = w & 3;
  const int lr = l & 15, lk = l >> 4;
  const int xm = (lr & 7) << 4;
  const int ck0 = (lk * 16) ^ xm;
  const int ck1 = (64 + lk * 16) ^ xm;
  const int bm = blockIdx.x, bn = blockIdx.y;

  const int rr = (w << 3) + (l >> 3);
  const int cE = ((l & 7) ^ (l >> 3)) << 3;
  const int dstoff = w * 1024 + l * 16;

  const ushort_t* sA00 = A + (size_t)(bm * 256 +       rr) * K + cE;
  const ushort_t* sA01 = A + (size_t)(bm * 256 +  64 + rr) * K + cE;
  const ushort_t* sA10 = A + (size_t)(bm * 256 + 128 + rr) * K + cE;
  const ushort_t* sA11 = A + (size_t)(bm * 256 + 192 + rr) * K + cE;
  int rb0 = bn * 256 +       rr; if (rb0 > NB - 1) rb0 = NB - 1;
  int rb1 = bn * 256 +  64 + rr; if (rb1 > NB - 1) rb1 = NB - 1;
  int rb2 = bn * 256 + 128 + rr; if (rb2 > NB - 1) rb2 = NB - 1;
  int rb3 = bn * 256 + 192 + rr; if (rb3 > NB - 1) rb3 = NB - 1;
  const ushort_t* sB00 = B + (size_t)rb0 * K + cE;
  const ushort_t* sB01 = B + (size_t)rb1 * K + cE;
  const ushort_t* sB10 = B + (size_t)rb2 * K + cE;
  const ushort_t* sB11 = B + (size_t)rb3 * K + cE;

  const int aoff = wr * 16384 + lr * 128;
  const int boff = 32768 + (wc >> 1) * 16384 + ((wc & 1) * 64 + lr) * 128;

  f32x4 acc[8][4] = {};
  bf16x8 af[4][2], bf[2][2], bg[2][2];

  stage2(sA00, sA01, lds + dstoff);
  stage2(sA10, sA11, lds + 16384 + dstoff);
  stage2(sB00, sB01, lds + 32768 + dstoff);
  stage2(sB10, sB11, lds + 49152 + dstoff);
  stage2(sA00 + 64, sA01 + 64, lds + 65536 + dstoff);
  VMCNT(2);
  BAR;

  auto kpair = [&](int kt0, bool last) {
    const unsigned char* a0 = lds + aoff;
    const unsigned char* b0 = lds + boff;
    const unsigned char* a1 = lds + 65536 + aoff;
    const unsigned char* b1 = lds + 65536 + boff;
    const size_t c1 = (size_t)(kt0 + 1) * 64;
    const size_t c2 = (size_t)(kt0 + 2) * 64;
    const size_t c3 = (size_t)(kt0 + 3) * 64;
    ld_a4(a0, 0, ck0, ck1, af);
    ld_b2(b0, 0, ck0, ck1, bf);
    stage2(sA10 + c1, sA11 + c1, lds + 65536 + 16384 + dstoff);
    BAR; LGKM0; mm16(acc, af, bf, 0, 0); BAR;
    ld_b2(b0, 32, ck0, ck1, bg);
    stage2(sB00 + c1, sB01 + c1, lds + 65536 + 32768 + dstoff);
    BAR; LGKM0; mm16(acc, af, bg, 0, 2); BAR;
    ld_a4(a0, 64, ck0, ck1, af);
    stage2(sB10 + c1, sB11 + c1, lds + 65536 + 49152 + dstoff);
    BAR; LGKM0; mm16(acc, af, bg, 4, 2); BAR;
    ld_b2(b0, 0, ck0, ck1, bf);
    if (!last) { stage2(sA00 + c2, sA01 + c2, lds + dstoff); VMCNT(2); }
    else       { VMCNT(0); }
    BAR; LGKM0; mm16(acc, af, bf, 4, 0); BAR;
    ld_a4(a1, 0, ck0, ck1, af);
    ld_b2(b1, 0, ck0, ck1, bf);
    if (!last) stage2(sA10 + c2, sA11 + c2, lds + 16384 + dstoff);
    BAR; LGKM0; mm16(acc, af, bf, 0, 0); BAR;
    ld_b2(b1, 32, ck0, ck1, bg);
    if (!last) stage2(sB00 + c2, sB01 + c2, lds + 32768 + dstoff);
    BAR; LGKM0; mm16(acc, af, bg, 0, 2); BAR;
    ld_a4(a1, 64, ck0, ck1, af);
    if (!last) stage2(sB10 + c2, sB11 + c2, lds + 49152 + dstoff);
    BAR; LGKM0; mm16(acc, af, bg, 4, 2); BAR;
    ld_b2(b1, 0, ck0, ck1, bf);
    if (!last) { stage2(sA00 + c3, sA01 + c3, lds + 65536 + dstoff); VMCNT(2); }
    BAR; LGKM0; mm16(acc, af, bf, 4, 0); BAR;
  };

  for (int it = 0; it < niter - 1; ++it) kpair(2 * it, false);
  kpair(2 * (niter - 1), true);

  const int crow0 = bm * 256 + wr * 128 + (lk << 2);
  const int ccol0 = bn * 256 + wc * 64 + lr;
  if (MODE == 0) {
    ushort_t* gate = (ushort_t*)C0;
    ushort_t* xbc  = (ushort_t*)C1;
#pragma unroll
    for (int ni = 0; ni < 4; ++ni) {
      const int col = ccol0 + ni * 16;
      if (col < NC) {
        ushort_t* dst; size_t stride;
        if (col < 4096) { dst = gate + col; stride = 4096; }
        else            { dst = xbc + (col - 4096); stride = 6272; }
#pragma unroll
        for (int mi = 0; mi < 8; ++mi)
#pragma unroll
          for (int r = 0; r < 4; ++r)
            dst[(size_t)(crow0 + mi * 16 + r) * stride] = f2bf(acc[mi][ni][r]);
      }
    }
  } else {
    float* o = (float*)C0;
#pragma unroll
    for (int ni = 0; ni < 4; ++ni) {
      const int col = ccol0 + ni * 16;
      if (col < NC) {
#pragma unroll
        for (int mi = 0; mi < 8; ++mi)
#pragma unroll
          for (int r = 0; r < 4; ++r)
            o[(size_t)(crow0 + mi * 16 + r) * NC + col] = acc[mi][ni][r];
      }
    }
  }
}

// ---------------- causal depthwise conv (K=4) + bias + SiLU, bf16 in/out ------
__global__ __launch_bounds__(256) void conv_silu_kernel(const ushort_t* __restrict__ xbc,
                                                        const float* __restrict__ cw,
                                                        const float* __restrict__ cb,
                                                        ushort_t* __restrict__ out) {
  int idx = blockIdx.x * 256 + threadIdx.x;      // 4096*1536
  int c4 = (idx % 1536) << 2;
  int bt = idx / 1536;
  int t = bt & 2047;
  const ushort_t* base = xbc + (size_t)bt * 6272 + c4;
  f32x4 w0 = *(const f32x4*)&cw[(c4 + 0) * 4];
  f32x4 w1 = *(const f32x4*)&cw[(c4 + 1) * 4];
  f32x4 w2 = *(const f32x4*)&cw[(c4 + 2) * 4];
  f32x4 w3 = *(const f32x4*)&cw[(c4 + 3) * 4];
  f32x4 acc = *(const f32x4*)&cb[c4];
#pragma unroll
  for (int i = 0; i < 4; ++i) {
    int dt_ = i - 3;
    if (t + dt_ >= 0) {
      u16x4 xv = *(const u16x4*)(base + (ptrdiff_t)dt_ * 6272);
      acc.x += bf2f(xv.x) * w0[i];
      acc.y += bf2f(xv.y) * w1[i];
      acc.z += bf2f(xv.z) * w2[i];
      acc.w += bf2f(xv.w) * w3[i];
    }
  }
  u16x4 o;
  o.x = f2bf(siluf(acc.x)); o.y = f2bf(siluf(acc.y));
  o.z = f2bf(siluf(acc.z)); o.w = f2bf(siluf(acc.w));
  *(u16x4*)(out + (size_t)bt * 6144 + c4) = o;
}

// ---------------- dt: softplus + exp(A*dt), layout [H][2][BT] f32 -------------
__global__ __launch_bounds__(256) void dt_kernel(const ushort_t* __restrict__ xbc,
                                                 const float* __restrict__ dt_bias,
                                                 const float* __restrict__ Avec,
                                                 float* __restrict__ dtA) {
  int idx = blockIdx.x * 256 + threadIdx.x;      // 64*4096
  int h = idx >> 12, bt = idx & 4095;
  float v = bf2f(xbc[(size_t)bt * 6272 + 6144 + h]) + dt_bias[h];
  float sp = fmaxf(v, 0.f) + log1pf(expf(-fabsf(v)));
  float ab = expf(Avec[h] * sp);
  dtA[(h << 13) + bt] = sp;
  dtA[(h << 13) + 4096 + bt] = ab;
}

// ---------------- scan pass 1: zero-init, emit y, write final state ----------
// grid 1024 = B(2) x H(64) x Chunk(8); thread = 4p x 8n = 32 states.
// NEW (R9): per 8-step block, one cooperative EXPAND phase converts staged
// bf16 x/B/C to f32 LDS once (kills the 16x-replicated per-thread cvt+extract
// that dominated VALU issue). Expand is fenced with lgkmcnt(0)+s_barrier only
// (no vmcnt drain — the tb+1 prefetch stays in flight; full __syncthreads at
// loop top drains it one iteration later).
__global__ __launch_bounds__(256) void scan_pass1_kernel(const ushort_t* __restrict__ conv,
                                                         const float* __restrict__ dtA,
                                                         const float* __restrict__ Dvec,
                                                         const float* __restrict__ Avec,
                                                         ushort_t* __restrict__ yssm,
                                                         ushort_t* __restrict__ hst,
                                                         float* __restrict__ abprod) {
  const int bid = blockIdx.x;
  const int ck = bid & 7;
  const int h = (bid >> 3) & 63;
  const int b = bid >> 9;
  const int g = h >> 3;
  const int tid = threadIdx.x;
  const int lane = tid & 63;
  const int wave = tid >> 6;
  const int pg = tid & 15, ng = tid >> 4;
  const int p0 = pg << 2, n0 = (ng & 15) << 3;

  // sraw per buf (bf16/f32 staging): x bf16[8][64] @0, B @1024, C @3072,
  //   dt f32[8] @5120, ab f32[8] @5152 -> 5184 B (324 x 16B chunks)
  // exp (single buffer, f32): x[8][64] @0, B[8][128] @2048B, C @6144B = 10240 B
  __shared__ __align__(16) unsigned char sraw[2][5184];
  __shared__ __align__(16) float expf32[2560];
  __shared__ __align__(16) float ypart[2][4][8][64];

  const int btbase = (b << 11) + (ck << 8);
  const float* dt0 = dtA + (h << 13) + btbase;
  const float* dt1 = dt0 + 4096;
  const float Dh = Dvec[h];
  const int xcol = h << 6;

  auto stage = [&](int tb) {
    unsigned char* dst = sraw[tb & 1];
    const int t0 = tb << 3;
    const size_t row0 = (size_t)(btbase + t0) * 6144;
#pragma unroll
    for (int j = 0; j < 2; ++j) {
      int c = tid + (j << 8);
      if (c < 324) {
        const void* src;
        if (c < 64)       { src = conv + row0 + (size_t)(c >> 3) * 6144 + xcol + ((c & 7) << 3); }
        else if (c < 192) { int r = c - 64;  src = conv + row0 + (size_t)(r >> 4) * 6144 + 4096 + (g << 7) + ((r & 15) << 3); }
        else if (c < 320) { int r = c - 192; src = conv + row0 + (size_t)(r >> 4) * 6144 + 5120 + (g << 7) + ((r & 15) << 3); }
        else if (c < 322) { src = dt0 + t0 + ((c - 320) << 2); }
        else              { src = dt1 + t0 + ((c - 322) << 2); }
        gload_lds16(src, dst + ((size_t)c << 4));
      }
    }
  };

  stage(0);

  f32x2 hsA[8], hsB[8];           // p0,p0+1 and p0+2,p0+3
#pragma unroll
  for (int n = 0; n < 8; ++n) { hsA[n] = (f32x2)(0.f); hsB[n] = (f32x2)(0.f); }
  float dtsum = 0.f;

  for (int tb = 0; tb < 32; ++tb) {
    __syncthreads();                 // full drain: stage(tb) data now visible
    if (tb > 0) {
      const int cur = (tb - 1) & 1;
      const int tprev = btbase + ((tb - 1) << 3);
#pragma unroll
      for (int r2 = 0; r2 < 2; ++r2) {
        int idx = tid + (r2 << 8);
        int tt = idx >> 6, p = idx & 63;
        float v = ypart[cur][0][tt][p] + ypart[cur][1][tt][p] +
                  ypart[cur][2][tt][p] + ypart[cur][3][tt][p];
        yssm[(size_t)(tprev + tt) * 4096 + xcol + p] = f2bf(v);
      }
    }
    if (tb + 1 < 32) stage(tb + 1);  // prefetch (stays in flight across exp bar)
    // ---- expand: bf16 sraw[tb&1] elems [0,2560) -> f32 expf32 ----
    {
      const ushort_t* sb16 = (const ushort_t*)sraw[tb & 1];
#pragma unroll
      for (int j = 0; j < 3; ++j) {
        int q = tid + (j << 8);
        if (q < 640) {
          u16x4 v = *(const u16x4*)&sb16[q << 2];
          f32x4 o;
          o.x = bf2f(v.x); o.y = bf2f(v.y); o.z = bf2f(v.z); o.w = bf2f(v.w);
          *(f32x4*)&expf32[q << 2] = o;
        }
      }
    }
    __builtin_amdgcn_sched_barrier(0);
    asm volatile("s_waitcnt lgkmcnt(0)" ::: "memory");
    __builtin_amdgcn_s_barrier();
    __builtin_amdgcn_sched_barrier(0);

    const float* ex = expf32;          // [8][64]
    const float* eb = expf32 + 512;    // [8][128]
    const float* ec = expf32 + 1536;   // [8][128]
    const float* sfs = (const float*)(sraw[tb & 1] + 5120);
    const int cur = tb & 1;
#pragma unroll
    for (int tt = 0; tt < 8; ++tt) {
      f32x4 xv = *(const f32x4*)&ex[(tt << 6) + p0];
      f32x2 xa, xb;
      xa.x = xv.x; xa.y = xv.y;
      xb.x = xv.z; xb.y = xv.w;
      f32x4 b0 = *(const f32x4*)&eb[(tt << 7) + n0];
      f32x4 b1 = *(const f32x4*)&eb[(tt << 7) + n0 + 4];
      f32x4 c0 = *(const f32x4*)&ec[(tt << 7) + n0];
      f32x4 c1 = *(const f32x4*)&ec[(tt << 7) + n0 + 4];
      const float dtv = sfs[tt], abv = sfs[8 + tt];
      dtsum += dtv;
      f32x2 ab2; ab2.x = abv; ab2.y = abv;
      f32x2 da = dtv * xa, db = dtv * xb;
      f32x2 ya = (f32x2)(0.f), yb = (f32x2)(0.f);
#pragma unroll
      for (int n = 0; n < 8; ++n) {
        const float Bn = (n < 4) ? b0[n] : b1[n - 4];
        const float Cn = (n < 4) ? c0[n] : c1[n - 4];
        f32x2 b2; b2.x = Bn; b2.y = Bn;
        f32x2 c2; c2.x = Cn; c2.y = Cn;
        hsA[n] = ab2 * hsA[n] + da * b2;  ya += hsA[n] * c2;
        hsB[n] = ab2 * hsB[n] + db * b2;  yb += hsB[n] * c2;
      }
      float y0 = ya.x, y1 = ya.y, y2 = yb.x, y3 = yb.y;
      y0 += __shfl_xor(y0, 16, 64); y0 += __shfl_xor(y0, 32, 64);
      y1 += __shfl_xor(y1, 16, 64); y1 += __shfl_xor(y1, 32, 64);
      y2 += __shfl_xor(y2, 16, 64); y2 += __shfl_xor(y2, 32, 64);
      y3 += __shfl_xor(y3, 16, 64); y3 += __shfl_xor(y3, 32, 64);
      if (wave == 0) {
        y0 += Dh * xa.x; y1 += Dh * xa.y;
        y2 += Dh * xb.x; y3 += Dh * xb.y;
      }
      if ((lane >> 4) == 0) {
        f32x4 o; o.x = y0; o.y = y1; o.z = y2; o.w = y3;
        *(f32x4*)&ypart[cur][wave][tt][p0] = o;
      }
    }
  }
  // final chunk state (zero-init scan) + abprod — layout identical to R7/R8:
  // hst[((b<<10)|(h<<4)|(ph<<3)|ck)*4096 + (p&31)*128 + n]
  {
#pragma unroll
    for (int i = 0; i < 4; ++i) {
      const int p = p0 + i;
      const size_t hb = ((size_t)((b << 10) | (h << 4) | ((p >> 5) << 3) | ck)) * 4096;
      u16x8 o;
      if (i < 2) {
#pragma unroll
        for (int n = 0; n < 8; ++n) o[n] = f2bf((i == 0) ? hsA[n].x : hsA[n].y);
      } else {
#pragma unroll
        for (int n = 0; n < 8; ++n) o[n] = f2bf((i == 2) ? hsB[n].x : hsB[n].y);
      }
      *(u16x8*)&hst[hb + (size_t)(p & 31) * 128 + n0] = o;
    }
    if (tid == 0)
      abprod[((b << 6) + h) * 8 + ck] = expf(Avec[h] * dtsum);
  }
  __syncthreads();
  {
    const int cur = 31 & 1;
    const int tprev = btbase + (31 << 3);
#pragma unroll
    for (int r2 = 0; r2 < 2; ++r2) {
      int idx = tid + (r2 << 8);
      int tt = idx >> 6, p = idx & 63;
      float v = ypart[cur][0][tt][p] + ypart[cur][1][tt][p] +
                ypart[cur][2][tt][p] + ypart[cur][3][tt][p];
      yssm[(size_t)(tprev + tt) * 4096 + xcol + p] = f2bf(v);
    }
  }
}

// ---------------- combine: prefix over chunk states (in place) ----------------
__global__ __launch_bounds__(256) void combine_kernel(ushort_t* __restrict__ hst,
                                                      const float* __restrict__ abprod) {
  const int bid = blockIdx.x;
  const int bh = bid >> 1;
  const int tid = threadIdx.x;
  const size_t base = (size_t)bid * 8 * 4096 + tid * 16;
  float hrun[16];
#pragma unroll
  for (int e = 0; e < 16; ++e) hrun[e] = 0.f;
  for (int c = 0; c < 8; ++c) {
    const size_t p = base + (size_t)c * 4096;
    u16x8 v0 = *(const u16x8*)&hst[p];
    u16x8 v1 = *(const u16x8*)&hst[p + 8];
    float ab = abprod[bh * 8 + c];
    u16x8 w0, w1;
#pragma unroll
    for (int e = 0; e < 8; ++e) { w0[e] = f2bf(hrun[e]); w1[e] = f2bf(hrun[8 + e]); }
    *(u16x8*)&hst[p] = w0;
    *(u16x8*)&hst[p + 8] = w1;
#pragma unroll
    for (int e = 0; e < 8; ++e) {
      hrun[e] = ab * hrun[e] + bf2f(v0[e]);
      hrun[8 + e] = ab * hrun[8 + e] + bf2f(v1[e]);
    }
  }
}

// ---------------- correction: yssm += pd[t] * (C_t . H_init) ------------------
__global__ __launch_bounds__(256) void correct_kernel(const ushort_t* __restrict__ conv,
                                                      const float* __restrict__ dtA,
                                                      const float* __restrict__ Avec,
                                                      const ushort_t* __restrict__ hst,
                                                      ushort_t* __restrict__ yssm) {
  const int bid = blockIdx.x;
  const int ck = bid & 7;
  const int h = (bid >> 3) & 63;
  const int b = bid >> 9;
  const int g = h >> 3;
  const int tid = threadIdx.x;
  const int lane = tid & 63;
  const int w = tid >> 6;
  const int lr = lane & 15, lk = lane >> 4;
  const int btb = (b << 11) + (ck << 8);

  __shared__ float pdl[256];
  __shared__ float wsum[4];
  float s = dtA[(h << 13) + btb + tid];
#pragma unroll
  for (int off = 1; off < 64; off <<= 1) {
    float t = __shfl_up(s, off, 64);
    if (lane >= off) s += t;
  }
  if (lane == 63) wsum[w] = s;
  __syncthreads();
  float basev = 0.f;
  for (int i = 0; i < w; ++i) basev += wsum[i];
  pdl[tid] = expf(Avec[h] * (basev + s));
  __syncthreads();

  const ushort_t* Cc = conv + (size_t)btb * 6144 + 5120 + (g << 7);
  const size_t hb0 = ((size_t)((b << 10) | (h << 4) | (0 << 3) | ck)) * 4096;
  const size_t hb1 = ((size_t)((b << 10) | (h << 4) | (1 << 3) | ck)) * 4096;

  f32x4 acc[4][4] = {};
#pragma unroll
  for (int kk = 0; kk < 4; ++kk) {
    const int k0 = kk * 32 + lk * 8;
    bf16x8 afr[4], bfr[4];
#pragma unroll
    for (int mf = 0; mf < 4; ++mf) {
      const int t = w * 64 + mf * 16 + lr;
      afr[mf] = *(const bf16x8*)(Cc + (size_t)t * 6144 + k0);
    }
#pragma unroll
    for (int nf = 0; nf < 4; ++nf) {
      const int p = nf * 16 + lr;
      const size_t hb = (p < 32) ? hb0 : hb1;
      bfr[nf] = *(const bf16x8*)(hst + hb + (size_t)(p & 31) * 128 + k0);
    }
#pragma unroll
    for (int mf = 0; mf < 4; ++mf)
#pragma unroll
      for (int nf = 0; nf < 4; ++nf)
        acc[mf][nf] = __builtin_amdgcn_mfma_f32_16x16x32_bf16(afr[mf], bfr[nf],
                                                              acc[mf][nf], 0, 0, 0);
  }

#pragma unroll
  for (int mf = 0; mf < 4; ++mf) {
#pragma unroll
    for (int r = 0; r < 4; ++r) {
      const int row = w * 64 + mf * 16 + (lk << 2) + r;
      const float pd = pdl[row];
      const size_t yrow = (size_t)(btb + row) * 4096 + (h << 6);
#pragma unroll
      for (int nf = 0; nf < 4; ++nf) {
        const int p = nf * 16 + lr;
        const size_t idx = yrow + p;
        yssm[idx] = f2bf(bf2f(yssm[idx]) + pd * acc[mf][nf][r]);
      }
    }
  }
}

// ---------------- gate * silu + RMSNorm -> bf16 -------------------------------
__global__ __launch_bounds__(256) void norm_kernel(const ushort_t* __restrict__ yssm,
                                                   const ushort_t* __restrict__ gate,
                                                   const float* __restrict__ nw,
                                                   ushort_t* __restrict__ out) {
  const int bt = blockIdx.x;
  const int tid = threadIdx.x;
  const ushort_t* y = yssm + (size_t)bt * 4096;
  const ushort_t* gt = gate + (size_t)bt * 4096;
  float vals[16];
  float ss = 0.f;
#pragma unroll
  for (int j = 0; j < 4; ++j) {
    int o = (tid + j * 256) << 2;
    u16x4 yv = *(const u16x4*)(y + o);
    u16x4 gv = *(const u16x4*)(gt + o);
#pragma unroll
    for (int e = 0; e < 4; ++e) {
      float v = bf2f(yv[e]) * siluf(bf2f(gv[e]));
      vals[j * 4 + e] = v;
      ss += v * v;
    }
  }
#pragma unroll
  for (int m = 1; m <= 32; m <<= 1) ss += __shfl_xor(ss, m, 64);
  __shared__ float red[4];
  if ((tid & 63) == 0) red[tid >> 6] = ss;
  __syncthreads();
  ss = red[0] + red[1] + red[2] + red[3];
  const float sc = rsqrtf(ss * (1.f / 4096.f) + 1e-5f);
#pragma unroll
  for (int j = 0; j < 4; ++j) {
    int o = (tid + j * 256) << 2;
    f32x4 wv = *(const f32x4*)(nw + o);
    u16x4 ov;
    ov.x = f2bf(vals[j * 4 + 0] * sc * wv.x);
    ov.y = f2bf(vals[j * 4 + 1] * sc * wv.y);
    ov.z = f2bf(vals[j * 4 + 2] * sc * wv.z);
    ov.w = f2bf(vals[j * 4 + 3] * sc * wv.w);
    *(u16x4*)(out + (size_t)bt * 4096 + o) = ov;
  }
}

// ------------------------------------------------------------------------------
extern "C" void kernel_launch(void* const* d_in, const int* in_sizes, int n_in,
                              void* d_out, int out_size, void* d_ws, size_t ws_size,
                              hipStream_t stream) {
  const float* hidden  = (const float*)d_in[0];
  const float* w_in    = (const float*)d_in[1];
  const float* conv_w  = (const float*)d_in[2];
  const float* conv_b  = (const float*)d_in[3];
  const float* Avec    = (const float*)d_in[4];
  const float* Dvec    = (const float*)d_in[5];
  const float* dt_bias = (const float*)d_in[6];
  const float* nw      = (const float*)d_in[7];
  const float* w_out   = (const float*)d_in[8];
  float* out = (float*)d_out;

  char* ws = (char*)d_ws;
  // Region map (total 162,693,120 B) — unchanged from R4/R6/R7/R8.
  ushort_t* Xbf   = (ushort_t*)(ws);
  ushort_t* W1bf  = (ushort_t*)(ws + 22020096);
  ushort_t* gate  = (ushort_t*)(ws + 77758464);
  ushort_t* xbc   = (ushort_t*)(ws + 111312896);
  ushort_t* W2bf  = Xbf;
  ushort_t* convb = W1bf;
  float*    dtA   = (float*)(ws + 22020096 + 50331648);
  float*    abprod= (float*)(ws + 22020096 + 52428800);
  ushort_t* yssm  = xbc;
  ushort_t* hst   = (ushort_t*)(ws + 111312896 + 33554432);
  ushort_t* ynorm = convb;
  const size_t NEED = 162693120;
  if (NEED > ws_size) {
    fill_kernel<<<4, 256, 0, stream>>>(out, 12345.0f, 1024);   // sentinel: ws too small
    return;
  }

  cvt_bf16_kernel<<<10752, 256, 0, stream>>>(hidden, Xbf, 2752512, 2752512);
  cvt_bf16_kernel<<<27216, 256, 0, stream>>>(w_in, W1bf, 6924288, 6967296);
  gemm8_kernel<0><<<dim3(16, 41), 512, 0, stream>>>(Xbf, W1bf, gate, xbc,
                                                    2688, 10368, 10304, 21);
  cvt_bf16_kernel<<<10752, 256, 0, stream>>>(w_out, W2bf, 2752512, 2752512);
  conv_silu_kernel<<<24576, 256, 0, stream>>>(xbc, conv_w, conv_b, convb);
  dt_kernel<<<1024, 256, 0, stream>>>(xbc, dt_bias, Avec, dtA);
  scan_pass1_kernel<<<1024, 256, 0, stream>>>(convb, dtA, Dvec, Avec, yssm, hst, abprod);
  combine_kernel<<<256, 256, 0, stream>>>(hst, abprod);
  correct_kernel<<<1024, 256, 0, stream>>>(convb, dtA, Avec, hst, yssm);
  norm_kernel<<<4096, 256, 0, stream>>>(yssm, gate, nw, ynorm);
  gemm8_kernel<1><<<dim3(16, 11), 512, 0, stream>>>(ynorm, W2bf, out, nullptr,
                                                    4096, 2688, 2688, 32);
}